// Round 12
// baseline (356.800 us; speedup 1.0000x reference)
//
#include <hip/hip_runtime.h>
#include <hip/hip_bf16.h>
#include <math.h>

// Problem dims
#define Bn 16
#define Sn 128
#define Rn 4
#define Ln 50
#define En 64
#define Hn 64
#define Vn 1000
#define G3 192          // 3*H
#define PH1n 256
#define PH2n 64
#define NSEQ (Bn*Sn*Rn) // 8192
#define NROW (Bn*Sn)    // 2048
#define GP 16

typedef short bf16x8 __attribute__((ext_vector_type(8)));
typedef float f32x4  __attribute__((ext_vector_type(4)));
typedef unsigned uint2v __attribute__((ext_vector_type(2)));

__device__ __forceinline__ unsigned short f2bf(float x) {
    union { float f; unsigned u; } v; v.f = x;
    unsigned r = v.u + 0x7FFF + ((v.u >> 16) & 1);   // RNE
    return (unsigned short)(r >> 16);
}
__device__ __forceinline__ float bf2f(unsigned short b) {
    union { unsigned u; float f; } v; v.u = ((unsigned)b) << 16; return v.f;
}
__device__ __forceinline__ float bf_lo(unsigned u) {
    union { unsigned x; float f; } v; v.x = u << 16; return v.f;
}
__device__ __forceinline__ float bf_hi(unsigned u) {
    union { unsigned x; float f; } v; v.x = u & 0xffff0000u; return v.f;
}
__device__ __forceinline__ unsigned cvtpk_bf16(float lo, float hi) {
    unsigned r;
    asm volatile("v_cvt_pk_bf16_f32 %0, %1, %2" : "=v"(r) : "v"(lo), "v"(hi));
    return r;
}
__device__ __forceinline__ float fsig(float x) {
    float e = __builtin_amdgcn_exp2f(-x * 1.442695041f);
    return __builtin_amdgcn_rcpf(1.0f + e);
}
__device__ __forceinline__ float ftanh(float x) {
    float e = __builtin_amdgcn_exp2f(x * 2.885390082f);
    return 1.0f - 2.0f * __builtin_amdgcn_rcpf(e + 1.0f);
}

// Raw barrier: LDS-drain only; global loads/stores float across.
#define BAR() do { asm volatile("s_waitcnt lgkmcnt(0)" ::: "memory"); \
                   __builtin_amdgcn_s_barrier(); \
                   __builtin_amdgcn_sched_barrier(0); } while (0)

// Un-sinkable 3 gate-loads (f32 table): p[0], p[64], p[128].
__device__ __forceinline__ void gload3(const float* p, float& a, float& b, float& c) {
    asm volatile("global_load_dword %0, %3, off\n\t"
                 "global_load_dword %1, %3, off offset:256\n\t"
                 "global_load_dword %2, %3, off offset:512"
                 : "=&v"(a), "=&v"(b), "=&v"(c) : "v"(p));
}
// Un-sinkable 3 gate-loads (bf16 permuted table): b64 each, gates at +128B/+256B.
__device__ __forceinline__ void gload2_3(const unsigned short* p, uint2v& a, uint2v& b, uint2v& c) {
    asm volatile("global_load_dwordx2 %0, %3, off\n\t"
                 "global_load_dwordx2 %1, %3, off offset:128\n\t"
                 "global_load_dwordx2 %2, %3, off offset:256"
                 : "=&v"(a), "=&v"(b), "=&v"(c) : "v"(p));
}

// ---------------------------------------------------------------------------
// Kernel A: bias-folded input-projection tables.
//  blocks [0,Vn):      pre_h[v][j] = bi_h[j] + (j<128 ? bh_h[j] : 0) + emb[v]·Wi_h[:,j]   (f32)
//  blocks [Vn,Vn+NROW): xwp (bf16, permuted [row][g][c][ct]):
//      val = bi_x[j] + (j<128 ? bh_x[j] : 0) + emb[id]·Wi_x[:,j] + ysh·Wi_x[64,j]
// ---------------------------------------------------------------------------
__global__ __launch_bounds__(192) void precompute_tab(
    const float* __restrict__ emb,
    const float* __restrict__ Wi_h, const float* __restrict__ bi_h,
    const float* __restrict__ bh_h,
    const float* __restrict__ Wi_x, const float* __restrict__ bi_x,
    const float* __restrict__ bh_x,
    const int*   __restrict__ intra_x, const float* __restrict__ y,
    float* __restrict__ pre_h, unsigned short* __restrict__ xwp)
{
    const int bx = blockIdx.x;
    const int j = threadIdx.x;            // 0..191
    __shared__ float e_l[En];
    if (bx < Vn) {
        if (j < En) e_l[j] = emb[bx * En + j];
        __syncthreads();
        float a = bi_h[j] + (j < 128 ? bh_h[j] : 0.0f);
#pragma unroll 8
        for (int k = 0; k < En; ++k) a = fmaf(e_l[k], Wi_h[k * G3 + j], a);
        pre_h[bx * G3 + j] = a;
    } else {
        const int row = bx - Vn;          // row = b*Sn + t
        const int id = intra_x[row];
        const float lb = (row & (Sn - 1)) ? y[row - 1] : 0.0f;
        if (j < En) e_l[j] = emb[id * En + j];
        __syncthreads();
        float a = bi_x[j] + (j < 128 ? bh_x[j] : 0.0f);
#pragma unroll 8
        for (int k = 0; k < En; ++k) a = fmaf(e_l[k], Wi_x[k * G3 + j], a);
        a = fmaf(lb, Wi_x[64 * G3 + j], a);
        const int g = j >> 6, cc = j & 63, ct = cc >> 4, c = cc & 15;
        xwp[(row * 3 + g) * 64 + c * 4 + ct] = f2bf(a);
    }
}

// ---------------------------------------------------------------------------
// Kernel B: grid 257.
//   block 0      : intra GRU — 4 REDUNDANT waves (each computes all 16 seqs ×
//                  192 gates; private LDS h-buffer; NO barriers in the loop).
//   blocks 1..256: peer GRU — DUAL groups of 16 seqs per block, phases fused
//                  so the compiler interleaves both groups' chains.
// ---------------------------------------------------------------------------
__global__ __launch_bounds__(256, 2) void gru_fused(
    const float* __restrict__ pre_h, const unsigned short* __restrict__ xwp,
    const int*   __restrict__ inter_his, const int* __restrict__ inter_len,
    const float* __restrict__ Wh_h, const float* __restrict__ bh_h,
    const float* __restrict__ Wi_h,
    const float* __restrict__ Wh_x, const float* __restrict__ bh_x,
    unsigned short* __restrict__ mrv16, float* __restrict__ h_x)
{
    __shared__ __align__(16) unsigned short ibuf[4][2][1024];   // intra: per-wave dbuf
    __shared__ __align__(16) unsigned short ph16[2][2][1024];   // peer: per-group dbuf
    __shared__ int   ids_l[2 * GP][Ln];
    __shared__ float labs_l[2 * GP][Ln];

    const int tid = threadIdx.x;
    const int lane = tid & 63, w = tid >> 6;
    const int n_ = lane & 15, kb = lane >> 4;

    if (blockIdx.x == 0) {
        // =============== INTRA (redundant 4x waves, barrier-free) ===========
        const int c = n_, g4 = kb;
        const int sq0 = g4 * 4;                   // C rows owned by this lane
        const unsigned arow = (unsigned)(n_ * 128);
        const unsigned ac0  = (unsigned)((kb * 16) ^ ((n_ & 7) << 4));
        const unsigned ac1  = (unsigned)((64 + kb * 16) ^ ((n_ & 7) << 4));
        {   // zero own buffer 0 (same-wave visibility only)
            unsigned* zb = (unsigned*)&ibuf[w][0][0];
#pragma unroll
            for (int i = 0; i < 8; ++i) zb[lane + 64 * i] = 0;
        }
        // B fragments: all 3 gates x 4 col-tiles x 2 K-halves (96 VGPRs)
        bf16x8 bfr[3][4][2];
#pragma unroll
        for (int g = 0; g < 3; ++g)
#pragma unroll
            for (int ct = 0; ct < 4; ++ct)
#pragma unroll
                for (int kh = 0; kh < 2; ++kh) {
                    bf16x8 v;
#pragma unroll
                    for (int i = 0; i < 8; ++i)
                        v[i] = (short)f2bf(Wh_x[(kh * 32 + g4 * 8 + i) * G3 + g * 64 + ct * 16 + c]);
                    bfr[g][ct][kh] = v;
                }
        float bhn_ct[4];
#pragma unroll
        for (int ct = 0; ct < 4; ++ct) bhn_ct[ct] = bh_x[128 + ct * 16 + c];
        unsigned iwoff[4][4];
#pragma unroll
        for (int i = 0; i < 4; ++i)
#pragma unroll
            for (int ct = 0; ct < 4; ++ct) {
                int row = sq0 + i;
                iwoff[i][ct] = (unsigned)(row * 128 + ((2 * (ct * 16 + c)) ^ ((row & 7) << 4)));
            }
        float hprev[4][4];
#pragma unroll
        for (int i = 0; i < 4; ++i)
#pragma unroll
            for (int ct = 0; ct < 4; ++ct) hprev[i][ct] = 0.0f;

        const unsigned short* px0 = xwp + (sq0 + 0) * (Sn * 192) + c * 4;
        const unsigned short* px1 = xwp + (sq0 + 1) * (Sn * 192) + c * 4;
        const unsigned short* px2 = xwp + (sq0 + 2) * (Sn * 192) + c * 4;
        const unsigned short* px3 = xwp + (sq0 + 3) * (Sn * 192) + c * 4;
        const bool w0 = (w == 0);

        uint2v Ar[4], Az[4], An_[4];
        uint2v Br[4], Bz[4], Bn_[4];
        gload2_3(px0, Ar[0], Az[0], An_[0]);
        gload2_3(px1, Ar[1], Az[1], An_[1]);
        gload2_3(px2, Ar[2], Az[2], An_[2]);
        gload2_3(px3, Ar[3], Az[3], An_[3]);

        auto istep = [&](int t, int cur,
                         uint2v (&gr)[4], uint2v (&gz)[4], uint2v (&gn)[4],
                         uint2v (&pr)[4], uint2v (&pz)[4], uint2v (&pn)[4]) {
            const char* rb = (const char*)&ibuf[w][cur][0];
            bf16x8 a0 = *(const bf16x8*)(rb + arow + ac0);
            bf16x8 a1 = *(const bf16x8*)(rb + arow + ac1);
            if (t + 1 < Sn) { px0 += 192; px1 += 192; px2 += 192; px3 += 192; }
            gload2_3(px0, pr[0], pz[0], pn[0]);
            gload2_3(px1, pr[1], pz[1], pn[1]);
            gload2_3(px2, pr[2], pz[2], pn[2]);
            gload2_3(px3, pr[3], pz[3], pn[3]);
            asm volatile("s_waitcnt vmcnt(12)" ::: "memory");
            __builtin_amdgcn_sched_barrier(0);
            f32x4 aR[4], aZ[4], aN[4];
#pragma unroll
            for (int ct = 0; ct < 4; ++ct) {
                f32x4 cr, cz, cn;
#pragma unroll
                for (int i = 0; i < 4; ++i) {
                    unsigned ur = gr[i][ct >> 1], uz = gz[i][ct >> 1];
                    cr[i] = (ct & 1) ? bf_hi(ur) : bf_lo(ur);
                    cz[i] = (ct & 1) ? bf_hi(uz) : bf_lo(uz);
                    cn[i] = bhn_ct[ct];
                }
                aR[ct] = __builtin_amdgcn_mfma_f32_16x16x32_bf16(a0, bfr[0][ct][0], cr, 0, 0, 0);
                aZ[ct] = __builtin_amdgcn_mfma_f32_16x16x32_bf16(a0, bfr[1][ct][0], cz, 0, 0, 0);
                aN[ct] = __builtin_amdgcn_mfma_f32_16x16x32_bf16(a0, bfr[2][ct][0], cn, 0, 0, 0);
                aR[ct] = __builtin_amdgcn_mfma_f32_16x16x32_bf16(a1, bfr[0][ct][1], aR[ct], 0, 0, 0);
                aZ[ct] = __builtin_amdgcn_mfma_f32_16x16x32_bf16(a1, bfr[1][ct][1], aZ[ct], 0, 0, 0);
                aN[ct] = __builtin_amdgcn_mfma_f32_16x16x32_bf16(a1, bfr[2][ct][1], aN[ct], 0, 0, 0);
            }
            char* wb = (char*)&ibuf[w][cur ^ 1][0];
#pragma unroll
            for (int i = 0; i < 4; ++i) {
#pragma unroll
                for (int ct = 0; ct < 4; ++ct) {
                    unsigned un = gn[i][ct >> 1];
                    float xn = (ct & 1) ? bf_hi(un) : bf_lo(un);
                    float rg = fsig(aR[ct][i]);
                    float zg = fsig(aZ[ct][i]);
                    float ng = ftanh(fmaf(rg, aN[ct][i], xn));
                    float h  = ng + zg * (hprev[i][ct] - ng);
                    hprev[i][ct] = h;
                    *(unsigned short*)(wb + iwoff[i][ct]) = f2bf(h);
                    if (w0) h_x[((sq0 + i) * Sn + t) * Hn + ct * 16 + c] = h;
                }
            }
            // order ds_writes(t) before ds_reads(t+1); same wave, no barrier
            asm volatile("s_waitcnt lgkmcnt(0)" ::: "memory");
            __builtin_amdgcn_sched_barrier(0);
        };

        for (int t = 0; t < Sn; t += 2) {
            istep(t,     0, Ar, Az, An_, Br, Bz, Bn_);
            istep(t + 1, 1, Br, Bz, Bn_, Ar, Az, An_);
        }
        return;
    }

    // =============== DUAL PEER (2 groups of 16 seqs per block) =============
    const int seq0 = ((int)blockIdx.x - 1) * 32;
    const int jh = w * 16 + n_;
    const int rbase = kb * 4;
    const unsigned arow = (unsigned)(n_ * 128);
    const unsigned ac0  = (unsigned)((kb * 16) ^ ((n_ & 7) << 4));
    const unsigned ac1  = (unsigned)((64 + kb * 16) ^ ((n_ & 7) << 4));
    unsigned woff[4];
#pragma unroll
    for (int q = 0; q < 4; ++q) {
        int r = rbase + q;
        woff[q] = (unsigned)(r * 128 + ((jh * 2) ^ ((r & 7) << 4)));
    }
    for (int i = tid; i < 4096; i += 256) (&ph16[0][0][0])[i] = 0;
    for (int i = tid; i < 32 * Ln; i += 256) {
        int r = i / Ln, t = i % Ln;
        int base = ((seq0 + r) * Ln + t) * 2;
        ids_l[r][t]  = inter_his[base];
        labs_l[r][t] = (float)inter_his[base + 1];
    }
    bf16x8 bfr[3][2];                       // shared by both groups (Wh_h)
#pragma unroll
    for (int g = 0; g < 3; ++g)
#pragma unroll
        for (int kh = 0; kh < 2; ++kh) {
            bf16x8 v;
#pragma unroll
            for (int i = 0; i < 8; ++i)
                v[i] = (short)f2bf(Wh_h[(kh * 32 + kb * 8 + i) * G3 + g * 64 + jh]);
            bfr[g][kh] = v;
        }
    const float bhn = bh_h[128 + jh];
    const float wlr = Wi_h[64 * G3 + jh];
    const float wlz = Wi_h[64 * G3 + 64 + jh];
    const float wln = Wi_h[64 * G3 + 128 + jh];
    int lenr[2][4];
#pragma unroll
    for (int gi = 0; gi < 2; ++gi)
#pragma unroll
        for (int q = 0; q < 4; ++q)
            lenr[gi][q] = inter_len[seq0 + gi * 16 + rbase + q];
    float hprev[2][4];
#pragma unroll
    for (int gi = 0; gi < 2; ++gi)
#pragma unroll
        for (int q = 0; q < 4; ++q) hprev[gi][q] = 0.0f;

    __syncthreads();   // staging + zeros visible BEFORE any ids_l read

    float Ar[2][4], Az[2][4], An_[2][4], Al[2][4];
    float Br[2][4], Bz[2][4], Bn_[2][4], Bl[2][4];
#pragma unroll
    for (int gi = 0; gi < 2; ++gi)
#pragma unroll
        for (int q = 0; q < 4; ++q) {
            int id = ids_l[gi * 16 + rbase + q][0];
            Al[gi][q] = labs_l[gi * 16 + rbase + q][0];
            gload3(pre_h + id * G3 + jh, Ar[gi][q], Az[gi][q], An_[gi][q]);
        }

    auto step = [&](int t, int cur,
                    float (&gr)[2][4], float (&gz)[2][4], float (&gn)[2][4], float (&gl)[2][4],
                    float (&pr)[2][4], float (&pz)[2][4], float (&pn)[2][4], float (&pl)[2][4]) {
        bf16x8 a0g[2], a1g[2];
#pragma unroll
        for (int gi = 0; gi < 2; ++gi) {
            const char* rb = (const char*)&ph16[gi][cur][0];
            a0g[gi] = *(const bf16x8*)(rb + arow + ac0);
            a1g[gi] = *(const bf16x8*)(rb + arow + ac1);
        }
        const int tn = (t + 1 < Ln) ? t + 1 : t;
#pragma unroll
        for (int gi = 0; gi < 2; ++gi)
#pragma unroll
            for (int q = 0; q < 4; ++q) {
                int id = ids_l[gi * 16 + rbase + q][tn];
                pl[gi][q] = labs_l[gi * 16 + rbase + q][tn];
                gload3(pre_h + id * G3 + jh, pr[gi][q], pz[gi][q], pn[gi][q]);
            }
        asm volatile("s_waitcnt vmcnt(24)" ::: "memory");
        __builtin_amdgcn_sched_barrier(0);
        f32x4 acc0g[2], acc1g[2], acc2g[2];
#pragma unroll
        for (int gi = 0; gi < 2; ++gi) {
            f32x4 c0, c1, c2;
#pragma unroll
            for (int q = 0; q < 4; ++q) {
                c0[q] = fmaf(gl[gi][q], wlr, gr[gi][q]);
                c1[q] = fmaf(gl[gi][q], wlz, gz[gi][q]);
                c2[q] = bhn;
            }
            acc0g[gi] = __builtin_amdgcn_mfma_f32_16x16x32_bf16(a0g[gi], bfr[0][0], c0, 0, 0, 0);
            acc1g[gi] = __builtin_amdgcn_mfma_f32_16x16x32_bf16(a0g[gi], bfr[1][0], c1, 0, 0, 0);
            acc2g[gi] = __builtin_amdgcn_mfma_f32_16x16x32_bf16(a0g[gi], bfr[2][0], c2, 0, 0, 0);
            acc0g[gi] = __builtin_amdgcn_mfma_f32_16x16x32_bf16(a1g[gi], bfr[0][1], acc0g[gi], 0, 0, 0);
            acc1g[gi] = __builtin_amdgcn_mfma_f32_16x16x32_bf16(a1g[gi], bfr[1][1], acc1g[gi], 0, 0, 0);
            acc2g[gi] = __builtin_amdgcn_mfma_f32_16x16x32_bf16(a1g[gi], bfr[2][1], acc2g[gi], 0, 0, 0);
        }
#pragma unroll
        for (int gi = 0; gi < 2; ++gi) {
            char* wb = (char*)&ph16[gi][cur ^ 1][0];
            float hn[4];
#pragma unroll
            for (int q = 0; q < 4; ++q) {
                float xn = fmaf(gl[gi][q], wln, gn[gi][q]);
                float rg = fsig(acc0g[gi][q]);
                float zg = fsig(acc1g[gi][q]);
                float ng = ftanh(fmaf(rg, acc2g[gi][q], xn));
                float h  = ng + zg * (hprev[gi][q] - ng);
                hprev[gi][q] = h; hn[q] = h;
                if (t == lenr[gi][q] - 1)
                    mrv16[(seq0 + gi * 16 + rbase + q) * Hn + jh] = f2bf(h);
            }
            unsigned u01 = cvtpk_bf16(hn[0], hn[1]);
            unsigned u23 = cvtpk_bf16(hn[2], hn[3]);
            *(unsigned short*)(wb + woff[0]) = (unsigned short)u01;
            *(unsigned short*)(wb + woff[1]) = (unsigned short)(u01 >> 16);
            *(unsigned short*)(wb + woff[2]) = (unsigned short)u23;
            *(unsigned short*)(wb + woff[3]) = (unsigned short)(u23 >> 16);
        }
        BAR();
    };

    for (int t = 0; t < Ln; t += 2) {
        step(t,     0, Ar, Az, An_, Al, Br, Bz, Bn_, Bl);
        step(t + 1, 1, Br, Bz, Bn_, Bl, Ar, Az, An_, Al);
    }
}

// ---------------------------------------------------------------------------
// Kernel C: attention + MLP; 4 rows per block (round-10 proven code).
// ---------------------------------------------------------------------------
__global__ __launch_bounds__(256) void attn_mlp(
    const float* __restrict__ h_x, const unsigned short* __restrict__ mrv16,
    const float* __restrict__ emb, const int* __restrict__ inter_r,
    const float* __restrict__ y,
    const float* __restrict__ Wq,
    const float* __restrict__ Wo, const float* __restrict__ bo,
    const float* __restrict__ W1, const float* __restrict__ b1,
    const float* __restrict__ W2, const float* __restrict__ b2,
    const float* __restrict__ W3, const float* __restrict__ b3,
    float* __restrict__ out)
{
    const int r0 = blockIdx.x * 4;
    const int tid = threadIdx.x;
    __shared__ float sh[4][64], ql[4][64], Ml[4][4][64], scl[4][4], al[4][4];
    __shared__ float vv[4][132], ol[4][64], z1[4][PH1n], z2[4][64];
    __shared__ int   rid[4][4];
    __shared__ float rlab[4][4];

    { int rr = tid >> 6, j = tid & 63; sh[rr][j] = h_x[(r0 + rr) * Hn + j]; }
    for (int i = tid; i < 4 * 4 * 64; i += 256) {
        int rr = i >> 8, r = (i >> 6) & 3, j = i & 63;
        Ml[rr][r][j] = bf2f(mrv16[((r0 + rr) * Rn + r) * Hn + j]);
    }
    if (tid < 16) {
        int rr = tid >> 2, r = tid & 3;
        rid[rr][r]  = inter_r[((r0 + rr) * Rn + r) * 2];
        rlab[rr][r] = (float)inter_r[((r0 + rr) * Rn + r) * 2 + 1];
    }
    __syncthreads();
    if (tid < 64) {
        const int j = tid;
        float a0 = 0.f, a1 = 0.f, a2 = 0.f, a3 = 0.f;
#pragma unroll 4
        for (int k = 0; k < 64; ++k) {
            float wv = Wq[k * Hn + j];
            a0 = fmaf(sh[0][k], wv, a0); a1 = fmaf(sh[1][k], wv, a1);
            a2 = fmaf(sh[2][k], wv, a2); a3 = fmaf(sh[3][k], wv, a3);
        }
        ql[0][j] = a0; ql[1][j] = a1; ql[2][j] = a2; ql[3][j] = a3;
    }
    __syncthreads();
    if (tid < 16) {
        int rr = tid >> 2, r = tid & 3;
        float a = 0.f;
#pragma unroll 8
        for (int k = 0; k < 64; ++k) a = fmaf(ql[rr][k], Ml[rr][r][k], a);
        scl[rr][r] = a * 0.125f;
    }
    __syncthreads();
    if (tid < 4) {
        const int rr = tid;
        float m = fmaxf(fmaxf(scl[rr][0], scl[rr][1]), fmaxf(scl[rr][2], scl[rr][3]));
        float s = 0.f, e[4];
#pragma unroll
        for (int r = 0; r < 4; ++r) {
            e[r] = __builtin_amdgcn_exp2f((scl[rr][r] - m) * 1.442695041f); s += e[r];
        }
        float inv = __builtin_amdgcn_rcpf(s);
#pragma unroll
        for (int r = 0; r < 4; ++r) al[rr][r] = e[r] * inv;
    }
    __syncthreads();
    if (tid < 129) {
#pragma unroll
        for (int rr = 0; rr < 4; ++rr) {
            float a = 0.f;
#pragma unroll
            for (int r = 0; r < 4; ++r) {
                float val;
                if (tid < 64)       val = Ml[rr][r][tid];
                else if (tid < 128) val = emb[rid[rr][r] * En + (tid - 64)];
                else                val = rlab[rr][r];
                a = fmaf(al[rr][r], val, a);
            }
            vv[rr][tid] = a;
        }
    }
    __syncthreads();
    if (tid < 64) {
        const int j = tid;
        float a0 = bo[j], a1 = a0, a2 = a0, a3 = a0;
#pragma unroll 4
        for (int k = 0; k < 64; ++k) {
            float wv = Wo[k * Hn + j];
            a0 = fmaf(sh[0][k], wv, a0); a1 = fmaf(sh[1][k], wv, a1);
            a2 = fmaf(sh[2][k], wv, a2); a3 = fmaf(sh[3][k], wv, a3);
        }
#pragma unroll 4
        for (int k = 0; k < 129; ++k) {
            float wv = Wo[(64 + k) * Hn + j];
            a0 = fmaf(vv[0][k], wv, a0); a1 = fmaf(vv[1][k], wv, a1);
            a2 = fmaf(vv[2][k], wv, a2); a3 = fmaf(vv[3][k], wv, a3);
        }
        ol[0][j] = ftanh(a0); ol[1][j] = ftanh(a1);
        ol[2][j] = ftanh(a2); ol[3][j] = ftanh(a3);
    }
    __syncthreads();
    {
        const int j = tid;
        float a0 = b1[j], a1 = a0, a2 = a0, a3 = a0;
#pragma unroll 4
        for (int k = 0; k < 64; ++k) {
            float wv = W1[k * PH1n + j];
            a0 = fmaf(ol[0][k], wv, a0); a1 = fmaf(ol[1][k], wv, a1);
            a2 = fmaf(ol[2][k], wv, a2); a3 = fmaf(ol[3][k], wv, a3);
        }
        z1[0][j] = fmaxf(a0, 0.f); z1[1][j] = fmaxf(a1, 0.f);
        z1[2][j] = fmaxf(a2, 0.f); z1[3][j] = fmaxf(a3, 0.f);
    }
    __syncthreads();
    if (tid < 64) {
        const int j = tid;
        float a0 = b2[j], a1 = a0, a2 = a0, a3 = a0;
#pragma unroll 4
        for (int k = 0; k < PH1n; ++k) {
            float wv = W2[k * PH2n + j];
            a0 = fmaf(z1[0][k], wv, a0); a1 = fmaf(z1[1][k], wv, a1);
            a2 = fmaf(z1[2][k], wv, a2); a3 = fmaf(z1[3][k], wv, a3);
        }
        z2[0][j] = fmaxf(a0, 0.f); z2[1][j] = fmaxf(a1, 0.f);
        z2[2][j] = fmaxf(a2, 0.f); z2[3][j] = fmaxf(a3, 0.f);
    }
    __syncthreads();
    if (tid < 4) {
        const int rr = tid;
        float a = b3[0];
#pragma unroll 8
        for (int k = 0; k < 64; ++k) a = fmaf(z2[rr][k], W3[k], a);
        out[r0 + rr] = fsig(a);
        out[NROW + r0 + rr] = y[r0 + rr];
    }
}

// ---------------------------------------------------------------------------
extern "C" void kernel_launch(void* const* d_in, const int* in_sizes, int n_in,
                              void* d_out, int out_size, void* d_ws, size_t ws_size,
                              hipStream_t stream) {
    const int*   intra_x   = (const int*)d_in[0];
    const int*   inter_his = (const int*)d_in[1];
    const int*   inter_r   = (const int*)d_in[2];
    const float* y         = (const float*)d_in[3];
    const int*   inter_len = (const int*)d_in[5];
    const float* emb  = (const float*)d_in[6];
    const float* Wi_h = (const float*)d_in[7];
    const float* Wh_h = (const float*)d_in[8];
    const float* bi_h = (const float*)d_in[9];
    const float* bh_h = (const float*)d_in[10];
    const float* Wi_x = (const float*)d_in[11];
    const float* Wh_x = (const float*)d_in[12];
    const float* bi_x = (const float*)d_in[13];
    const float* bh_x = (const float*)d_in[14];
    const float* Wq = (const float*)d_in[15];
    const float* Wo = (const float*)d_in[16];
    const float* bo = (const float*)d_in[17];
    const float* W1 = (const float*)d_in[18];
    const float* b1 = (const float*)d_in[19];
    const float* W2 = (const float*)d_in[20];
    const float* b2 = (const float*)d_in[21];
    const float* W3 = (const float*)d_in[22];
    const float* b3 = (const float*)d_in[23];

    float* out = (float*)d_out;
    float* ws  = (float*)d_ws;
    // workspace (float slots): pre_h 192000 | xwp 786432 ushort = 196608 |
    // mrv16 524288 ushort = 262144 | h_x 131072   => 3.13 MB total
    float*          pre_h = ws;
    unsigned short* xwp   = (unsigned short*)(ws + 192000);
    unsigned short* mrv16 = (unsigned short*)(ws + 388608);
    float*          h_x   = ws + 650752;

    precompute_tab<<<Vn + NROW, 192, 0, stream>>>(emb, Wi_h, bi_h, bh_h,
                                                  Wi_x, bi_x, bh_x,
                                                  intra_x, y, pre_h, xwp);
    gru_fused<<<1 + NSEQ / 32, 256, 0, stream>>>(pre_h, xwp, inter_his, inter_len,
                                                 Wh_h, bh_h, Wi_h,
                                                 Wh_x, bh_x,
                                                 mrv16, h_x);
    attn_mlp<<<NROW / 4, 256, 0, stream>>>(h_x, mrv16, emb, inter_r, y,
                                           Wq, Wo, bo, W1, b1, W2, b2, W3, b3, out);
}

// Round 13
// 105.286 us; speedup vs baseline: 3.3889x; 3.3889x over previous
//
#include <hip/hip_runtime.h>
#include <hip/hip_bf16.h>
#include <math.h>

// Problem dims
#define Bn 16
#define Sn 128
#define Rn 4
#define Ln 50
#define En 64
#define Hn 64
#define Vn 1000
#define G3 192          // 3*H
#define PH1n 256
#define PH2n 64
#define NSEQ (Bn*Sn*Rn) // 8192
#define NROW (Bn*Sn)    // 2048
#define GP 16           // sequences per block (MFMA M-tile)

typedef short bf16x8 __attribute__((ext_vector_type(8)));
typedef float f32x4  __attribute__((ext_vector_type(4)));

__device__ __forceinline__ unsigned short f2bf(float x) {
    union { float f; unsigned u; } v; v.f = x;
    unsigned r = v.u + 0x7FFF + ((v.u >> 16) & 1);   // RNE
    return (unsigned short)(r >> 16);
}
__device__ __forceinline__ float bf2f(unsigned short b) {
    union { unsigned u; float f; } v; v.u = ((unsigned)b) << 16; return v.f;
}
__device__ __forceinline__ unsigned cvtpk_bf16(float lo, float hi) {
    unsigned r;
    asm volatile("v_cvt_pk_bf16_f32 %0, %1, %2" : "=v"(r) : "v"(lo), "v"(hi));
    return r;
}
// fast sigmoid/tanh: v_exp_f32 (2^x) + v_rcp_f32
__device__ __forceinline__ float fsig(float x) {
    float e = __builtin_amdgcn_exp2f(-x * 1.442695041f);
    return __builtin_amdgcn_rcpf(1.0f + e);
}
__device__ __forceinline__ float ftanh(float x) {
    float e = __builtin_amdgcn_exp2f(x * 2.885390082f);
    return 1.0f - 2.0f * __builtin_amdgcn_rcpf(e + 1.0f);
}

// Raw barrier: LDS-drain only; global loads/stores float across.
#define BAR() do { asm volatile("s_waitcnt lgkmcnt(0)" ::: "memory"); \
                   __builtin_amdgcn_s_barrier(); \
                   __builtin_amdgcn_sched_barrier(0); } while (0)

// Un-sinkable 3 gate-loads: p[0], p[64], p[128].
__device__ __forceinline__ void gload3(const float* p, float& a, float& b, float& c) {
    asm volatile("global_load_dword %0, %3, off\n\t"
                 "global_load_dword %1, %3, off offset:256\n\t"
                 "global_load_dword %2, %3, off offset:512"
                 : "=&v"(a), "=&v"(b), "=&v"(c) : "v"(p));
}

// ---------------------------------------------------------------------------
// Kernel A: blocks [0, Vn)       : pre_h[v][j] = bi_h[j] + emb[v]·Wi_h[:,j]
//           blocks [Vn, Vn+NROW) : xw[row][j]  = bi_x[j] + emb[id]·Wi_x[:,j]
//                                  + y_sh·Wi_x[64,j]
// ---------------------------------------------------------------------------
__global__ __launch_bounds__(192) void precompute_tab(
    const float* __restrict__ emb,
    const float* __restrict__ Wi_h, const float* __restrict__ bi_h,
    const float* __restrict__ Wi_x, const float* __restrict__ bi_x,
    const int*   __restrict__ intra_x, const float* __restrict__ y,
    float* __restrict__ pre_h, float* __restrict__ xw)
{
    const int bx = blockIdx.x;
    const int j = threadIdx.x;            // 0..191
    __shared__ float e_l[En];
    if (bx < Vn) {
        if (j < En) e_l[j] = emb[bx * En + j];
        __syncthreads();
        float a = bi_h[j];
#pragma unroll 8
        for (int k = 0; k < En; ++k) a = fmaf(e_l[k], Wi_h[k * G3 + j], a);
        pre_h[bx * G3 + j] = a;
    } else {
        const int row = bx - Vn;          // row = b*Sn + t
        const int id = intra_x[row];
        const float lb = (row & (Sn - 1)) ? y[row - 1] : 0.0f;
        if (j < En) e_l[j] = emb[id * En + j];
        __syncthreads();
        float a = bi_x[j];
#pragma unroll 8
        for (int k = 0; k < En; ++k) a = fmaf(e_l[k], Wi_x[k * G3 + j], a);
        a = fmaf(lb, Wi_x[64 * G3 + j], a);
        xw[row * G3 + j] = a;
    }
}

// ---------------------------------------------------------------------------
// Kernel B: unified MFMA GRU, raw barriers, asm-pinned gather prefetch.
//   block 0        : intra GRU — M=16 batch sequences, nT=128, linear xw reads
//   blocks 1..512  : peer GRU  — M=16 peer sequences,  nT=50, pre_h gathers
// vmcnt discipline: per-step in-flight counts are UNIFORM so each wait retires
// exactly the previous step's loads and never drains store-acks.
// ---------------------------------------------------------------------------
__global__ __launch_bounds__(256, 2) void gru_fused(
    const float* __restrict__ pre_h, const float* __restrict__ xw,
    const int*   __restrict__ inter_his, const int* __restrict__ inter_len,
    const float* __restrict__ Wh_h, const float* __restrict__ bh_h,
    const float* __restrict__ Wi_h,
    const float* __restrict__ Wh_x, const float* __restrict__ bh_x,
    unsigned short* __restrict__ mrv16, float* __restrict__ h_x)
{
    __shared__ __align__(16) unsigned short h16[2][GP * 64];  // 2 x 2KB, swizzled
    __shared__ int   ids_l[GP][Ln];
    __shared__ float labs_l[GP][Ln];

    const int tid = threadIdx.x;
    const int lane = tid & 63, w = tid >> 6;
    const int n_ = lane & 15, kb = lane >> 4;
    const int jh = w * 16 + n_;          // this wave's hidden-column
    const int rbase = kb * 4;            // C rows (sequences) owned by this lane

    // addr(row, bytecol) = row*128 + (bytecol ^ ((row&7)<<4))
    const unsigned arow = (unsigned)(n_ * 128);
    const unsigned ac0  = (unsigned)((kb * 16) ^ ((n_ & 7) << 4));
    const unsigned ac1  = (unsigned)((64 + kb * 16) ^ ((n_ & 7) << 4));
    unsigned woff[4];
#pragma unroll
    for (int q = 0; q < 4; ++q) {
        int r = rbase + q;
        woff[q] = (unsigned)(r * 128 + ((jh * 2) ^ ((r & 7) << 4)));
    }
    for (int i = tid; i < GP * 64; i += 256) h16[0][i] = 0;

    if (blockIdx.x != 0) {
        // =============== PEER GRU ===============
        const int seq0 = ((int)blockIdx.x - 1) * GP;
        for (int i = tid; i < GP * Ln; i += 256) {
            int r = i / Ln, t = i % Ln;
            int base = ((seq0 + r) * Ln + t) * 2;
            ids_l[r][t]  = inter_his[base];
            labs_l[r][t] = (float)inter_his[base + 1];
        }
        // B fragments: Wh_h[64][192] -> 3 gate-tiles x 2 K-halves in regs
        bf16x8 bfr[3][2];
#pragma unroll
        for (int g = 0; g < 3; ++g)
#pragma unroll
            for (int kh = 0; kh < 2; ++kh) {
                bf16x8 v;
#pragma unroll
                for (int i = 0; i < 8; ++i)
                    v[i] = (short)f2bf(Wh_h[(kh * 32 + kb * 8 + i) * G3 + g * 64 + jh]);
                bfr[g][kh] = v;
            }
        const float bhr = bh_h[jh], bhz = bh_h[64 + jh], bhn = bh_h[128 + jh];
        const float wlr = Wi_h[64 * G3 + jh];
        const float wlz = Wi_h[64 * G3 + 64 + jh];
        const float wln = Wi_h[64 * G3 + 128 + jh];
        int lenr[4];
#pragma unroll
        for (int q = 0; q < 4; ++q) lenr[q] = inter_len[seq0 + rbase + q];
        float hprev[4] = {0.f, 0.f, 0.f, 0.f};
        float mrvv[4] = {0.f, 0.f, 0.f, 0.f};   // deferred M_rv values

        float Ar[4], Az[4], An_[4], Al[4];
        float Br[4], Bz[4], Bn_[4], Bl[4];
#pragma unroll
        for (int q = 0; q < 4; ++q) {
            int id = ids_l[rbase + q][0];
            Al[q] = labs_l[rbase + q][0];
            gload3(pre_h + id * G3 + jh, Ar[q], Az[q], An_[q]);
        }
        __syncthreads();   // setup barrier: full drain (L_0 lands here)

        auto step = [&](int t, int cur,
                        float (&gr)[4], float (&gz)[4], float (&gn)[4], float (&gl)[4],
                        float (&pr)[4], float (&pz)[4], float (&pn)[4], float (&pl)[4]) {
            const char* rb = (const char*)&h16[cur][0];
            bf16x8 a0 = *(const bf16x8*)(rb + arow + ac0);
            bf16x8 a1 = *(const bf16x8*)(rb + arow + ac1);
            const int tn = (t + 1 < Ln) ? t + 1 : t;
#pragma unroll
            for (int q = 0; q < 4; ++q) {
                int id = ids_l[rbase + q][tn];
                pl[q] = labs_l[rbase + q][tn];
                gload3(pre_h + id * G3 + jh, pr[q], pz[q], pn[q]);
            }
            f32x4 z4 = {0.f, 0.f, 0.f, 0.f};
            f32x4 acc0 = __builtin_amdgcn_mfma_f32_16x16x32_bf16(a0, bfr[0][0], z4, 0, 0, 0);
            f32x4 acc1 = __builtin_amdgcn_mfma_f32_16x16x32_bf16(a0, bfr[1][0], z4, 0, 0, 0);
            f32x4 acc2 = __builtin_amdgcn_mfma_f32_16x16x32_bf16(a0, bfr[2][0], z4, 0, 0, 0);
            acc0 = __builtin_amdgcn_mfma_f32_16x16x32_bf16(a1, bfr[0][1], acc0, 0, 0, 0);
            acc1 = __builtin_amdgcn_mfma_f32_16x16x32_bf16(a1, bfr[1][1], acc1, 0, 0, 0);
            acc2 = __builtin_amdgcn_mfma_f32_16x16x32_bf16(a1, bfr[2][1], acc2, 0, 0, 0);

            // exactly 12 newer ops in flight (this step's loads, no stores):
            // retires the PREVIOUS step's 12 loads, nothing else.
            asm volatile("s_waitcnt vmcnt(12)" ::: "memory");
            __builtin_amdgcn_sched_barrier(0);

            char* wb = (char*)&h16[cur ^ 1][0];
            float hn[4];
#pragma unroll
            for (int q = 0; q < 4; ++q) {
                float xr = fmaf(gl[q], wlr, gr[q]);
                float xz = fmaf(gl[q], wlz, gz[q]);
                float xn = fmaf(gl[q], wln, gn[q]);
                float rg = fsig(xr + acc0[q] + bhr);
                float zg = fsig(xz + acc1[q] + bhz);
                float ng = ftanh(fmaf(rg, acc2[q] + bhn, xn));
                float h  = (1.0f - zg) * ng + zg * hprev[q];
                hprev[q] = h; hn[q] = h;
                mrvv[q] = (t == lenr[q] - 1) ? h : mrvv[q];  // defer store
            }
            unsigned u01 = cvtpk_bf16(hn[0], hn[1]);
            unsigned u23 = cvtpk_bf16(hn[2], hn[3]);
            *(unsigned short*)(wb + woff[0]) = (unsigned short)u01;
            *(unsigned short*)(wb + woff[1]) = (unsigned short)(u01 >> 16);
            *(unsigned short*)(wb + woff[2]) = (unsigned short)u23;
            *(unsigned short*)(wb + woff[3]) = (unsigned short)(u23 >> 16);
            BAR();   // LDS-drain only; loads stay in flight
        };

        for (int t = 0; t < Ln; t += 2) {
            step(t,     0, Ar, Az, An_, Al, Br, Bz, Bn_, Bl);
            step(t + 1, 1, Br, Bz, Bn_, Bl, Ar, Az, An_, Al);
        }
        // single unconditional M_rv store per (lane, q)
#pragma unroll
        for (int q = 0; q < 4; ++q)
            mrv16[(seq0 + rbase + q) * Hn + jh] = f2bf(mrvv[q]);
    } else {
        // =============== INTRA GRU (linear xw reads) ===============
        bf16x8 bfr[3][2];
#pragma unroll
        for (int g = 0; g < 3; ++g)
#pragma unroll
            for (int kh = 0; kh < 2; ++kh) {
                bf16x8 v;
#pragma unroll
                for (int i = 0; i < 8; ++i)
                    v[i] = (short)f2bf(Wh_x[(kh * 32 + kb * 8 + i) * G3 + g * 64 + jh]);
                bfr[g][kh] = v;
            }
        const float bhr = bh_x[jh], bhz = bh_x[64 + jh], bhn = bh_x[128 + jh];
        float hprev[4] = {0.f, 0.f, 0.f, 0.f};

        // per-sequence input pointers (advance by G3 per step) + h_x outputs
        const float* q0 = xw + (rbase + 0) * Sn * G3 + jh;
        const float* q1 = xw + (rbase + 1) * Sn * G3 + jh;
        const float* q2 = xw + (rbase + 2) * Sn * G3 + jh;
        const float* q3 = xw + (rbase + 3) * Sn * G3 + jh;
        float* p0 = h_x + (rbase + 0) * Sn * Hn + jh;
        float* p1 = h_x + (rbase + 1) * Sn * Hn + jh;
        float* p2 = h_x + (rbase + 2) * Sn * Hn + jh;
        float* p3 = h_x + (rbase + 3) * Sn * Hn + jh;

        float Ar[4], Az[4], An_[4];
        float Br[4], Bz[4], Bn_[4];
        gload3(q0, Ar[0], Az[0], An_[0]);
        gload3(q1, Ar[1], Az[1], An_[1]);
        gload3(q2, Ar[2], Az[2], An_[2]);
        gload3(q3, Ar[3], Az[3], An_[3]);
        __syncthreads();   // h16[0] zeros visible + L_0 drained

        auto istep = [&](int t, int cur,
                         float (&gr)[4], float (&gz)[4], float (&gn)[4],
                         float (&pr)[4], float (&pz)[4], float (&pn)[4]) {
            const char* rb = (const char*)&h16[cur][0];
            bf16x8 a0 = *(const bf16x8*)(rb + arow + ac0);
            bf16x8 a1 = *(const bf16x8*)(rb + arow + ac1);
            if (t + 1 < Sn) { q0 += G3; q1 += G3; q2 += G3; q3 += G3; }
            gload3(q0, pr[0], pz[0], pn[0]);   // 12 loads every step (uniform)
            gload3(q1, pr[1], pz[1], pn[1]);
            gload3(q2, pr[2], pz[2], pn[2]);
            gload3(q3, pr[3], pz[3], pn[3]);
            f32x4 z4 = {0.f, 0.f, 0.f, 0.f};
            f32x4 acc0 = __builtin_amdgcn_mfma_f32_16x16x32_bf16(a0, bfr[0][0], z4, 0, 0, 0);
            f32x4 acc1 = __builtin_amdgcn_mfma_f32_16x16x32_bf16(a0, bfr[1][0], z4, 0, 0, 0);
            f32x4 acc2 = __builtin_amdgcn_mfma_f32_16x16x32_bf16(a0, bfr[2][0], z4, 0, 0, 0);
            acc0 = __builtin_amdgcn_mfma_f32_16x16x32_bf16(a1, bfr[0][1], acc0, 0, 0, 0);
            acc1 = __builtin_amdgcn_mfma_f32_16x16x32_bf16(a1, bfr[1][1], acc1, 0, 0, 0);
            acc2 = __builtin_amdgcn_mfma_f32_16x16x32_bf16(a1, bfr[2][1], acc2, 0, 0, 0);

            // newer ops in flight: S_{t-1}(4) + L_{t+1}(12) = 16 (uniform for
            // t>=1; at t=0 loads were drained by __syncthreads). Retires L_t
            // WITHOUT forcing the previous step's h_x store-acks.
            asm volatile("s_waitcnt vmcnt(16)" ::: "memory");
            __builtin_amdgcn_sched_barrier(0);

            char* wb = (char*)&h16[cur ^ 1][0];
            float hn[4];
#pragma unroll
            for (int q = 0; q < 4; ++q) {
                float rg = fsig(gr[q] + acc0[q] + bhr);
                float zg = fsig(gz[q] + acc1[q] + bhz);
                float ng = ftanh(fmaf(rg, acc2[q] + bhn, gn[q]));
                float h  = (1.0f - zg) * ng + zg * hprev[q];
                hprev[q] = h; hn[q] = h;
            }
            unsigned u01 = cvtpk_bf16(hn[0], hn[1]);
            unsigned u23 = cvtpk_bf16(hn[2], hn[3]);
            *(unsigned short*)(wb + woff[0]) = (unsigned short)u01;
            *(unsigned short*)(wb + woff[1]) = (unsigned short)(u01 >> 16);
            *(unsigned short*)(wb + woff[2]) = (unsigned short)u23;
            *(unsigned short*)(wb + woff[3]) = (unsigned short)(u23 >> 16);
            *p0 = hn[0]; p0 += Hn;             // 4 stores per step (uniform)
            *p1 = hn[1]; p1 += Hn;
            *p2 = hn[2]; p2 += Hn;
            *p3 = hn[3]; p3 += Hn;
            BAR();
        };

        for (int t = 0; t < Sn; t += 2) {
            istep(t,     0, Ar, Az, An_, Br, Bz, Bn_);
            istep(t + 1, 1, Br, Bz, Bn_, Ar, Az, An_);
        }
    }
}

// ---------------------------------------------------------------------------
// Kernel C: attention + MLP; 4 rows per block (weight-load amortization).
// ---------------------------------------------------------------------------
__global__ __launch_bounds__(256) void attn_mlp(
    const float* __restrict__ h_x, const unsigned short* __restrict__ mrv16,
    const float* __restrict__ emb, const int* __restrict__ inter_r,
    const float* __restrict__ y,
    const float* __restrict__ Wq,
    const float* __restrict__ Wo, const float* __restrict__ bo,
    const float* __restrict__ W1, const float* __restrict__ b1,
    const float* __restrict__ W2, const float* __restrict__ b2,
    const float* __restrict__ W3, const float* __restrict__ b3,
    float* __restrict__ out)
{
    const int r0 = blockIdx.x * 4;        // rows r0..r0+3
    const int tid = threadIdx.x;
    __shared__ float sh[4][64], ql[4][64], Ml[4][4][64], scl[4][4], al[4][4];
    __shared__ float vv[4][132], ol[4][64], z1[4][PH1n], z2[4][64];
    __shared__ int   rid[4][4];
    __shared__ float rlab[4][4];

    { int rr = tid >> 6, j = tid & 63; sh[rr][j] = h_x[(r0 + rr) * Hn + j]; }
    for (int i = tid; i < 4 * 4 * 64; i += 256) {
        int rr = i >> 8, r = (i >> 6) & 3, j = i & 63;
        Ml[rr][r][j] = bf2f(mrv16[((r0 + rr) * Rn + r) * Hn + j]);
    }
    if (tid < 16) {
        int rr = tid >> 2, r = tid & 3;
        rid[rr][r]  = inter_r[((r0 + rr) * Rn + r) * 2];
        rlab[rr][r] = (float)inter_r[((r0 + rr) * Rn + r) * 2 + 1];
    }
    __syncthreads();
    if (tid < 64) {
        const int j = tid;
        float a0 = 0.f, a1 = 0.f, a2 = 0.f, a3 = 0.f;
#pragma unroll 4
        for (int k = 0; k < 64; ++k) {
            float wv = Wq[k * Hn + j];
            a0 = fmaf(sh[0][k], wv, a0); a1 = fmaf(sh[1][k], wv, a1);
            a2 = fmaf(sh[2][k], wv, a2); a3 = fmaf(sh[3][k], wv, a3);
        }
        ql[0][j] = a0; ql[1][j] = a1; ql[2][j] = a2; ql[3][j] = a3;
    }
    __syncthreads();
    if (tid < 16) {
        int rr = tid >> 2, r = tid & 3;
        float a = 0.f;
#pragma unroll 8
        for (int k = 0; k < 64; ++k) a = fmaf(ql[rr][k], Ml[rr][r][k], a);
        scl[rr][r] = a * 0.125f;
    }
    __syncthreads();
    if (tid < 4) {
        const int rr = tid;
        float m = fmaxf(fmaxf(scl[rr][0], scl[rr][1]), fmaxf(scl[rr][2], scl[rr][3]));
        float s = 0.f, e[4];
#pragma unroll
        for (int r = 0; r < 4; ++r) {
            e[r] = __builtin_amdgcn_exp2f((scl[rr][r] - m) * 1.442695041f); s += e[r];
        }
        float inv = __builtin_amdgcn_rcpf(s);
#pragma unroll
        for (int r = 0; r < 4; ++r) al[rr][r] = e[r] * inv;
    }
    __syncthreads();
    if (tid < 129) {
#pragma unroll
        for (int rr = 0; rr < 4; ++rr) {
            float a = 0.f;
#pragma unroll
            for (int r = 0; r < 4; ++r) {
                float val;
                if (tid < 64)       val = Ml[rr][r][tid];
                else if (tid < 128) val = emb[rid[rr][r] * En + (tid - 64)];
                else                val = rlab[rr][r];
                a = fmaf(al[rr][r], val, a);
            }
            vv[rr][tid] = a;
        }
    }
    __syncthreads();
    if (tid < 64) {
        const int j = tid;
        float a0 = bo[j], a1 = a0, a2 = a0, a3 = a0;
#pragma unroll 4
        for (int k = 0; k < 64; ++k) {
            float wv = Wo[k * Hn + j];
            a0 = fmaf(sh[0][k], wv, a0); a1 = fmaf(sh[1][k], wv, a1);
            a2 = fmaf(sh[2][k], wv, a2); a3 = fmaf(sh[3][k], wv, a3);
        }
#pragma unroll 4
        for (int k = 0; k < 129; ++k) {
            float wv = Wo[(64 + k) * Hn + j];
            a0 = fmaf(vv[0][k], wv, a0); a1 = fmaf(vv[1][k], wv, a1);
            a2 = fmaf(vv[2][k], wv, a2); a3 = fmaf(vv[3][k], wv, a3);
        }
        ol[0][j] = ftanh(a0); ol[1][j] = ftanh(a1);
        ol[2][j] = ftanh(a2); ol[3][j] = ftanh(a3);
    }
    __syncthreads();
    {
        const int j = tid;
        float a0 = b1[j], a1 = a0, a2 = a0, a3 = a0;
#pragma unroll 4
        for (int k = 0; k < 64; ++k) {
            float wv = W1[k * PH1n + j];
            a0 = fmaf(ol[0][k], wv, a0); a1 = fmaf(ol[1][k], wv, a1);
            a2 = fmaf(ol[2][k], wv, a2); a3 = fmaf(ol[3][k], wv, a3);
        }
        z1[0][j] = fmaxf(a0, 0.f); z1[1][j] = fmaxf(a1, 0.f);
        z1[2][j] = fmaxf(a2, 0.f); z1[3][j] = fmaxf(a3, 0.f);
    }
    __syncthreads();
    if (tid < 64) {
        const int j = tid;
        float a0 = b2[j], a1 = a0, a2 = a0, a3 = a0;
#pragma unroll 4
        for (int k = 0; k < PH1n; ++k) {
            float wv = W2[k * PH2n + j];
            a0 = fmaf(z1[0][k], wv, a0); a1 = fmaf(z1[1][k], wv, a1);
            a2 = fmaf(z1[2][k], wv, a2); a3 = fmaf(z1[3][k], wv, a3);
        }
        z2[0][j] = fmaxf(a0, 0.f); z2[1][j] = fmaxf(a1, 0.f);
        z2[2][j] = fmaxf(a2, 0.f); z2[3][j] = fmaxf(a3, 0.f);
    }
    __syncthreads();
    if (tid < 4) {
        const int rr = tid;
        float a = b3[0];
#pragma unroll 8
        for (int k = 0; k < 64; ++k) a = fmaf(z2[rr][k], W3[k], a);
        out[r0 + rr] = fsig(a);
        out[NROW + r0 + rr] = y[r0 + rr];
    }
}

// ---------------------------------------------------------------------------
extern "C" void kernel_launch(void* const* d_in, const int* in_sizes, int n_in,
                              void* d_out, int out_size, void* d_ws, size_t ws_size,
                              hipStream_t stream) {
    const int*   intra_x   = (const int*)d_in[0];
    const int*   inter_his = (const int*)d_in[1];
    const int*   inter_r   = (const int*)d_in[2];
    const float* y         = (const float*)d_in[3];
    const int*   inter_len = (const int*)d_in[5];
    const float* emb  = (const float*)d_in[6];
    const float* Wi_h = (const float*)d_in[7];
    const float* Wh_h = (const float*)d_in[8];
    const float* bi_h = (const float*)d_in[9];
    const float* bh_h = (const float*)d_in[10];
    const float* Wi_x = (const float*)d_in[11];
    const float* Wh_x = (const float*)d_in[12];
    const float* bi_x = (const float*)d_in[13];
    const float* bh_x = (const float*)d_in[14];
    const float* Wq = (const float*)d_in[15];
    const float* Wo = (const float*)d_in[16];
    const float* bo = (const float*)d_in[17];
    const float* W1 = (const float*)d_in[18];
    const float* b1 = (const float*)d_in[19];
    const float* W2 = (const float*)d_in[20];
    const float* b2 = (const float*)d_in[21];
    const float* W3 = (const float*)d_in[22];
    const float* b3 = (const float*)d_in[23];

    float* out = (float*)d_out;
    float* ws  = (float*)d_ws;
    // workspace (floats): pre_h 192000 | xw 393216 | mrv16 (524288 ushort =
    // 262144 float-slots) | h_x 131072  => 3.91 MB total
    float*          pre_h = ws;
    float*          xw    = ws + 192000;
    unsigned short* mrv16 = (unsigned short*)(ws + 585216);
    float*          h_x   = ws + 847360;

    precompute_tab<<<Vn + NROW, 192, 0, stream>>>(emb, Wi_h, bi_h, Wi_x, bi_x,
                                                  intra_x, y, pre_h, xw);
    gru_fused<<<1 + NSEQ / GP, 256, 0, stream>>>(pre_h, xw, inter_his, inter_len,
                                                 Wh_h, bh_h, Wi_h,
                                                 Wh_x, bh_x,
                                                 mrv16, h_x);
    attn_mlp<<<NROW / 4, 256, 0, stream>>>(h_x, mrv16, emb, inter_r, y,
                                           Wq, Wo, bo, W1, b1, W2, b2, W3, b3, out);
}

// Round 14
// 90.436 us; speedup vs baseline: 3.9453x; 1.1642x over previous
//
#include <hip/hip_runtime.h>
#include <hip/hip_bf16.h>
#include <math.h>

// Problem dims
#define Bn 16
#define Sn 128
#define Rn 4
#define Ln 50
#define En 64
#define Hn 64
#define Vn 1000
#define G3 192          // 3*H
#define PH1n 256
#define PH2n 64
#define NSEQ (Bn*Sn*Rn) // 8192
#define NROW (Bn*Sn)    // 2048
#define GP 16           // sequences per block (MFMA M-tile)

typedef short bf16x8 __attribute__((ext_vector_type(8)));
typedef float f32x4  __attribute__((ext_vector_type(4)));

__device__ __forceinline__ unsigned short f2bf(float x) {
    union { float f; unsigned u; } v; v.f = x;
    unsigned r = v.u + 0x7FFF + ((v.u >> 16) & 1);   // RNE
    return (unsigned short)(r >> 16);
}
__device__ __forceinline__ float bf2f(unsigned short b) {
    union { unsigned u; float f; } v; v.u = ((unsigned)b) << 16; return v.f;
}
__device__ __forceinline__ unsigned cvtpk_bf16(float lo, float hi) {
    unsigned r;
    asm volatile("v_cvt_pk_bf16_f32 %0, %1, %2" : "=v"(r) : "v"(lo), "v"(hi));
    return r;
}
// fast sigmoid/tanh: v_exp_f32 (2^x) + v_rcp_f32
__device__ __forceinline__ float fsig(float x) {
    float e = __builtin_amdgcn_exp2f(-x * 1.442695041f);
    return __builtin_amdgcn_rcpf(1.0f + e);
}
__device__ __forceinline__ float ftanh(float x) {
    float e = __builtin_amdgcn_exp2f(x * 2.885390082f);
    return 1.0f - 2.0f * __builtin_amdgcn_rcpf(e + 1.0f);
}

// Raw barrier: LDS-drain only; global loads/stores float across.
#define BAR() do { asm volatile("s_waitcnt lgkmcnt(0)" ::: "memory"); \
                   __builtin_amdgcn_s_barrier(); \
                   __builtin_amdgcn_sched_barrier(0); } while (0)

// Un-sinkable 3 gate-loads: p[0], p[64], p[128].
__device__ __forceinline__ void gload3(const float* p, float& a, float& b, float& c) {
    asm volatile("global_load_dword %0, %3, off\n\t"
                 "global_load_dword %1, %3, off offset:256\n\t"
                 "global_load_dword %2, %3, off offset:512"
                 : "=&v"(a), "=&v"(b), "=&v"(c) : "v"(p));
}

// pack table offsets (in ushorts): Wq 8 frags | Wo 28 | W1 32 | W2 32, 512 each
#define PK_WQ 0
#define PK_WO 4096
#define PK_W1 18432
#define PK_W2 34816

// ---------------------------------------------------------------------------
// Kernel A: blocks [0, Vn)            : pre_h table (f32)
//           blocks [Vn, Vn+NROW)      : xw table (f32, intra inputs)
//           blocks [Vn+NROW, +100)    : bf16 fragment-packed attn weights
// ---------------------------------------------------------------------------
__global__ __launch_bounds__(192) void precompute_tab(
    const float* __restrict__ emb,
    const float* __restrict__ Wi_h, const float* __restrict__ bi_h,
    const float* __restrict__ Wi_x, const float* __restrict__ bi_x,
    const int*   __restrict__ intra_x, const float* __restrict__ y,
    const float* __restrict__ Wq, const float* __restrict__ Wo,
    const float* __restrict__ W1, const float* __restrict__ W2,
    float* __restrict__ pre_h, float* __restrict__ xw,
    unsigned short* __restrict__ packs)
{
    const int bx = blockIdx.x;
    const int j = threadIdx.x;            // 0..191
    __shared__ float e_l[En];
    if (bx < Vn) {
        if (j < En) e_l[j] = emb[bx * En + j];
        __syncthreads();
        float a = bi_h[j];
#pragma unroll 8
        for (int k = 0; k < En; ++k) a = fmaf(e_l[k], Wi_h[k * G3 + j], a);
        pre_h[bx * G3 + j] = a;
    } else if (bx < Vn + NROW) {
        const int row = bx - Vn;          // row = b*Sn + t
        const int id = intra_x[row];
        const float lb = (row & (Sn - 1)) ? y[row - 1] : 0.0f;
        if (j < En) e_l[j] = emb[id * En + j];
        __syncthreads();
        float a = bi_x[j];
#pragma unroll 8
        for (int k = 0; k < En; ++k) a = fmaf(e_l[k], Wi_x[k * G3 + j], a);
        a = fmaf(lb, Wi_x[64 * G3 + j], a);
        xw[row * G3 + j] = a;
    } else if (j < 64) {
        // pack one B-fragment (frag = 16x... lane j holds W[k0+i][n], i<8)
        const int p = bx - (Vn + NROW);
        const float* W; int KH, N, Kmax, q; unsigned short* dst;
        if (p < 8)       { q = p;      W = Wq; KH = 2; N = 64;  Kmax = 64;  dst = packs + PK_WQ; }
        else if (p < 36) { q = p - 8;  W = Wo; KH = 7; N = 64;  Kmax = 193; dst = packs + PK_WO; }
        else if (p < 68) { q = p - 36; W = W1; KH = 2; N = 256; Kmax = 64;  dst = packs + PK_W1; }
        else             { q = p - 68; W = W2; KH = 8; N = 64;  Kmax = 256; dst = packs + PK_W2; }
        const int nt = q / KH, kh = q - nt * KH;
        const int n  = nt * 16 + (j & 15);
        const int k0 = kh * 32 + (j >> 4) * 8;
#pragma unroll
        for (int i = 0; i < 8; ++i) {
            int k = k0 + i;
            float v = (k < Kmax) ? W[k * N + n] : 0.0f;
            dst[q * 512 + j * 8 + i] = f2bf(v);
        }
    }
}

// ---------------------------------------------------------------------------
// Kernel B: unified MFMA GRU (unchanged from round 13 — proven).
// ---------------------------------------------------------------------------
__global__ __launch_bounds__(256, 2) void gru_fused(
    const float* __restrict__ pre_h, const float* __restrict__ xw,
    const int*   __restrict__ inter_his, const int* __restrict__ inter_len,
    const float* __restrict__ Wh_h, const float* __restrict__ bh_h,
    const float* __restrict__ Wi_h,
    const float* __restrict__ Wh_x, const float* __restrict__ bh_x,
    unsigned short* __restrict__ mrv16, float* __restrict__ h_x)
{
    __shared__ __align__(16) unsigned short h16[2][GP * 64];  // 2 x 2KB, swizzled
    __shared__ int   ids_l[GP][Ln];
    __shared__ float labs_l[GP][Ln];

    const int tid = threadIdx.x;
    const int lane = tid & 63, w = tid >> 6;
    const int n_ = lane & 15, kb = lane >> 4;
    const int jh = w * 16 + n_;
    const int rbase = kb * 4;

    const unsigned arow = (unsigned)(n_ * 128);
    const unsigned ac0  = (unsigned)((kb * 16) ^ ((n_ & 7) << 4));
    const unsigned ac1  = (unsigned)((64 + kb * 16) ^ ((n_ & 7) << 4));
    unsigned woff[4];
#pragma unroll
    for (int q = 0; q < 4; ++q) {
        int r = rbase + q;
        woff[q] = (unsigned)(r * 128 + ((jh * 2) ^ ((r & 7) << 4)));
    }
    for (int i = tid; i < GP * 64; i += 256) h16[0][i] = 0;

    if (blockIdx.x != 0) {
        // =============== PEER GRU ===============
        const int seq0 = ((int)blockIdx.x - 1) * GP;
        for (int i = tid; i < GP * Ln; i += 256) {
            int r = i / Ln, t = i % Ln;
            int base = ((seq0 + r) * Ln + t) * 2;
            ids_l[r][t]  = inter_his[base];
            labs_l[r][t] = (float)inter_his[base + 1];
        }
        bf16x8 bfr[3][2];
#pragma unroll
        for (int g = 0; g < 3; ++g)
#pragma unroll
            for (int kh = 0; kh < 2; ++kh) {
                bf16x8 v;
#pragma unroll
                for (int i = 0; i < 8; ++i)
                    v[i] = (short)f2bf(Wh_h[(kh * 32 + kb * 8 + i) * G3 + g * 64 + jh]);
                bfr[g][kh] = v;
            }
        const float bhr = bh_h[jh], bhz = bh_h[64 + jh], bhn = bh_h[128 + jh];
        const float wlr = Wi_h[64 * G3 + jh];
        const float wlz = Wi_h[64 * G3 + 64 + jh];
        const float wln = Wi_h[64 * G3 + 128 + jh];
        int lenr[4];
#pragma unroll
        for (int q = 0; q < 4; ++q) lenr[q] = inter_len[seq0 + rbase + q];
        float hprev[4] = {0.f, 0.f, 0.f, 0.f};
        float mrvv[4] = {0.f, 0.f, 0.f, 0.f};

        float Ar[4], Az[4], An_[4], Al[4];
        float Br[4], Bz[4], Bn_[4], Bl[4];
#pragma unroll
        for (int q = 0; q < 4; ++q) {
            int id = ids_l[rbase + q][0];
            Al[q] = labs_l[rbase + q][0];
            gload3(pre_h + id * G3 + jh, Ar[q], Az[q], An_[q]);
        }
        __syncthreads();

        auto step = [&](int t, int cur,
                        float (&gr)[4], float (&gz)[4], float (&gn)[4], float (&gl)[4],
                        float (&pr)[4], float (&pz)[4], float (&pn)[4], float (&pl)[4]) {
            const char* rb = (const char*)&h16[cur][0];
            bf16x8 a0 = *(const bf16x8*)(rb + arow + ac0);
            bf16x8 a1 = *(const bf16x8*)(rb + arow + ac1);
            const int tn = (t + 1 < Ln) ? t + 1 : t;
#pragma unroll
            for (int q = 0; q < 4; ++q) {
                int id = ids_l[rbase + q][tn];
                pl[q] = labs_l[rbase + q][tn];
                gload3(pre_h + id * G3 + jh, pr[q], pz[q], pn[q]);
            }
            f32x4 z4 = {0.f, 0.f, 0.f, 0.f};
            f32x4 acc0 = __builtin_amdgcn_mfma_f32_16x16x32_bf16(a0, bfr[0][0], z4, 0, 0, 0);
            f32x4 acc1 = __builtin_amdgcn_mfma_f32_16x16x32_bf16(a0, bfr[1][0], z4, 0, 0, 0);
            f32x4 acc2 = __builtin_amdgcn_mfma_f32_16x16x32_bf16(a0, bfr[2][0], z4, 0, 0, 0);
            acc0 = __builtin_amdgcn_mfma_f32_16x16x32_bf16(a1, bfr[0][1], acc0, 0, 0, 0);
            acc1 = __builtin_amdgcn_mfma_f32_16x16x32_bf16(a1, bfr[1][1], acc1, 0, 0, 0);
            acc2 = __builtin_amdgcn_mfma_f32_16x16x32_bf16(a1, bfr[2][1], acc2, 0, 0, 0);

            asm volatile("s_waitcnt vmcnt(12)" ::: "memory");
            __builtin_amdgcn_sched_barrier(0);

            char* wb = (char*)&h16[cur ^ 1][0];
            float hn[4];
#pragma unroll
            for (int q = 0; q < 4; ++q) {
                float xr = fmaf(gl[q], wlr, gr[q]);
                float xz = fmaf(gl[q], wlz, gz[q]);
                float xn = fmaf(gl[q], wln, gn[q]);
                float rg = fsig(xr + acc0[q] + bhr);
                float zg = fsig(xz + acc1[q] + bhz);
                float ng = ftanh(fmaf(rg, acc2[q] + bhn, xn));
                float h  = (1.0f - zg) * ng + zg * hprev[q];
                hprev[q] = h; hn[q] = h;
                mrvv[q] = (t == lenr[q] - 1) ? h : mrvv[q];
            }
            unsigned u01 = cvtpk_bf16(hn[0], hn[1]);
            unsigned u23 = cvtpk_bf16(hn[2], hn[3]);
            *(unsigned short*)(wb + woff[0]) = (unsigned short)u01;
            *(unsigned short*)(wb + woff[1]) = (unsigned short)(u01 >> 16);
            *(unsigned short*)(wb + woff[2]) = (unsigned short)u23;
            *(unsigned short*)(wb + woff[3]) = (unsigned short)(u23 >> 16);
            BAR();
        };

        for (int t = 0; t < Ln; t += 2) {
            step(t,     0, Ar, Az, An_, Al, Br, Bz, Bn_, Bl);
            step(t + 1, 1, Br, Bz, Bn_, Bl, Ar, Az, An_, Al);
        }
#pragma unroll
        for (int q = 0; q < 4; ++q)
            mrv16[(seq0 + rbase + q) * Hn + jh] = f2bf(mrvv[q]);
    } else {
        // =============== INTRA GRU (linear xw reads) ===============
        bf16x8 bfr[3][2];
#pragma unroll
        for (int g = 0; g < 3; ++g)
#pragma unroll
            for (int kh = 0; kh < 2; ++kh) {
                bf16x8 v;
#pragma unroll
                for (int i = 0; i < 8; ++i)
                    v[i] = (short)f2bf(Wh_x[(kh * 32 + kb * 8 + i) * G3 + g * 64 + jh]);
                bfr[g][kh] = v;
            }
        const float bhr = bh_x[jh], bhz = bh_x[64 + jh], bhn = bh_x[128 + jh];
        float hprev[4] = {0.f, 0.f, 0.f, 0.f};

        const float* q0 = xw + (rbase + 0) * Sn * G3 + jh;
        const float* q1 = xw + (rbase + 1) * Sn * G3 + jh;
        const float* q2 = xw + (rbase + 2) * Sn * G3 + jh;
        const float* q3 = xw + (rbase + 3) * Sn * G3 + jh;
        float* p0 = h_x + (rbase + 0) * Sn * Hn + jh;
        float* p1 = h_x + (rbase + 1) * Sn * Hn + jh;
        float* p2 = h_x + (rbase + 2) * Sn * Hn + jh;
        float* p3 = h_x + (rbase + 3) * Sn * Hn + jh;

        float Ar[4], Az[4], An_[4];
        float Br[4], Bz[4], Bn_[4];
        gload3(q0, Ar[0], Az[0], An_[0]);
        gload3(q1, Ar[1], Az[1], An_[1]);
        gload3(q2, Ar[2], Az[2], An_[2]);
        gload3(q3, Ar[3], Az[3], An_[3]);
        __syncthreads();

        auto istep = [&](int t, int cur,
                         float (&gr)[4], float (&gz)[4], float (&gn)[4],
                         float (&pr)[4], float (&pz)[4], float (&pn)[4]) {
            const char* rb = (const char*)&h16[cur][0];
            bf16x8 a0 = *(const bf16x8*)(rb + arow + ac0);
            bf16x8 a1 = *(const bf16x8*)(rb + arow + ac1);
            if (t + 1 < Sn) { q0 += G3; q1 += G3; q2 += G3; q3 += G3; }
            gload3(q0, pr[0], pz[0], pn[0]);
            gload3(q1, pr[1], pz[1], pn[1]);
            gload3(q2, pr[2], pz[2], pn[2]);
            gload3(q3, pr[3], pz[3], pn[3]);
            f32x4 z4 = {0.f, 0.f, 0.f, 0.f};
            f32x4 acc0 = __builtin_amdgcn_mfma_f32_16x16x32_bf16(a0, bfr[0][0], z4, 0, 0, 0);
            f32x4 acc1 = __builtin_amdgcn_mfma_f32_16x16x32_bf16(a0, bfr[1][0], z4, 0, 0, 0);
            f32x4 acc2 = __builtin_amdgcn_mfma_f32_16x16x32_bf16(a0, bfr[2][0], z4, 0, 0, 0);
            acc0 = __builtin_amdgcn_mfma_f32_16x16x32_bf16(a1, bfr[0][1], acc0, 0, 0, 0);
            acc1 = __builtin_amdgcn_mfma_f32_16x16x32_bf16(a1, bfr[1][1], acc1, 0, 0, 0);
            acc2 = __builtin_amdgcn_mfma_f32_16x16x32_bf16(a1, bfr[2][1], acc2, 0, 0, 0);

            asm volatile("s_waitcnt vmcnt(16)" ::: "memory");
            __builtin_amdgcn_sched_barrier(0);

            char* wb = (char*)&h16[cur ^ 1][0];
            float hn[4];
#pragma unroll
            for (int q = 0; q < 4; ++q) {
                float rg = fsig(gr[q] + acc0[q] + bhr);
                float zg = fsig(gz[q] + acc1[q] + bhz);
                float ng = ftanh(fmaf(rg, acc2[q] + bhn, gn[q]));
                float h  = (1.0f - zg) * ng + zg * hprev[q];
                hprev[q] = h; hn[q] = h;
            }
            unsigned u01 = cvtpk_bf16(hn[0], hn[1]);
            unsigned u23 = cvtpk_bf16(hn[2], hn[3]);
            *(unsigned short*)(wb + woff[0]) = (unsigned short)u01;
            *(unsigned short*)(wb + woff[1]) = (unsigned short)(u01 >> 16);
            *(unsigned short*)(wb + woff[2]) = (unsigned short)u23;
            *(unsigned short*)(wb + woff[3]) = (unsigned short)(u23 >> 16);
            *p0 = hn[0]; p0 += Hn;
            *p1 = hn[1]; p1 += Hn;
            *p2 = hn[2]; p2 += Hn;
            *p3 = hn[3]; p3 += Hn;
            BAR();
        };

        for (int t = 0; t < Sn; t += 2) {
            istep(t,     0, Ar, Az, An_, Br, Bz, Bn_);
            istep(t + 1, 1, Br, Bz, Bn_, Ar, Az, An_);
        }
    }
}

// ---------------------------------------------------------------------------
// Kernel C: MFMA attention + MLP; 16 rows per block, 128 blocks.
// All GEMMs (Wq, Wo, W1, W2) on matrix cores with bf16 fragment tables;
// scores/softmax/vv/W3 stay VALU (tiny). A-fragments use the GRU-verified
// XOR-swizzled LDS layout: addr = row*RS + (bytecol ^ ((row&7)<<4)).
// ---------------------------------------------------------------------------
__global__ __launch_bounds__(256) void attn_mlp(
    const float* __restrict__ h_x, const unsigned short* __restrict__ mrv16,
    const float* __restrict__ emb, const int* __restrict__ inter_r,
    const float* __restrict__ y,
    const unsigned short* __restrict__ packs,
    const float* __restrict__ bo, const float* __restrict__ b1,
    const float* __restrict__ b2,
    const float* __restrict__ W3, const float* __restrict__ b3,
    float* __restrict__ out)
{
    const int r0 = blockIdx.x * 16;
    const int tid = threadIdx.x;
    const int lane = tid & 63, w = tid >> 6;
    const int n_ = lane & 15, kb = lane >> 4;
    const unsigned sw = (unsigned)((n_ & 7) << 4);

    __shared__ __align__(16) char aauxB[16 * 512];   // [16][256] bf16: h|vv|0
    __shared__ __align__(16) char olB[16 * 128];     // [16][64]  bf16
    __shared__ __align__(16) char z1B[16 * 512];     // [16][256] bf16
    __shared__ float Mlf[16][4][65];
    __shared__ float qs[16][68];
    __shared__ float z2f[16][68];
    __shared__ float scl[16][4], al[16][4], rlab[16][4];
    __shared__ int   rid[16][4];

    const unsigned short* pWq = packs + PK_WQ;
    const unsigned short* pWo = packs + PK_WO;
    const unsigned short* pW1 = packs + PK_W1;
    const unsigned short* pW2 = packs + PK_W2;

    // ---- stage: zero aaux cols 64..255, h -> aaux cols 0..63, Ml, rid ----
    for (int i = tid; i < 16 * 96; i += 256) {
        int rr = i / 96, d = 32 + (i % 96);
        ((unsigned*)aauxB)[rr * 128 + d] = 0;
    }
    {
        int rr = tid >> 4, c4 = (tid & 15) * 4;
        float4 hv = *(const float4*)(h_x + (r0 + rr) * Hn + c4);
        unsigned lo = cvtpk_bf16(hv.x, hv.y), hi = cvtpk_bf16(hv.z, hv.w);
        unsigned off = (unsigned)(rr * 512) + (((unsigned)(2 * c4)) ^ ((rr & 7) << 4));
        *(unsigned*)(aauxB + off) = lo;
        *(unsigned*)(aauxB + off + 4) = hi;
    }
    for (int i = tid; i < 4096; i += 256) {
        int rr = i >> 8, rem = i & 255, r = rem >> 6, k = rem & 63;
        Mlf[rr][r][k] = bf2f(mrv16[((r0 + rr) * Rn + r) * Hn + k]);
    }
    if (tid < 64) {
        int rr = tid >> 2, r = tid & 3;
        rid[rr][r]  = inter_r[((r0 + rr) * Rn + r) * 2];
        rlab[rr][r] = (float)inter_r[((r0 + rr) * Rn + r) * 2 + 1];
    }
    __syncthreads();

    // ---- Wq GEMM: q[16][64] (wave w -> cols w*16..w*16+15) ----
    {
        bf16x8 a0 = *(const bf16x8*)(aauxB + n_ * 512 + ((0 * 64 + kb * 16) ^ sw));
        bf16x8 a1 = *(const bf16x8*)(aauxB + n_ * 512 + ((1 * 64 + kb * 16) ^ sw));
        bf16x8 b0 = *(const bf16x8*)(pWq + (w * 2 + 0) * 512 + lane * 8);
        bf16x8 b1v = *(const bf16x8*)(pWq + (w * 2 + 1) * 512 + lane * 8);
        f32x4 z4 = {0.f, 0.f, 0.f, 0.f};
        f32x4 qa = __builtin_amdgcn_mfma_f32_16x16x32_bf16(a0, b0, z4, 0, 0, 0);
        qa = __builtin_amdgcn_mfma_f32_16x16x32_bf16(a1, b1v, qa, 0, 0, 0);
#pragma unroll
        for (int q = 0; q < 4; ++q) qs[kb * 4 + q][w * 16 + n_] = qa[q];
    }
    __syncthreads();

    // ---- scores ----
    if (tid < 64) {
        int rr = tid >> 2, r = tid & 3;
        float a = 0.f;
#pragma unroll 8
        for (int k = 0; k < 64; ++k) a = fmaf(qs[rr][k], Mlf[rr][r][k], a);
        scl[rr][r] = a * 0.125f;
    }
    __syncthreads();
    if (tid < 16) {
        float m = fmaxf(fmaxf(scl[tid][0], scl[tid][1]), fmaxf(scl[tid][2], scl[tid][3]));
        float s = 0.f, e[4];
#pragma unroll
        for (int r = 0; r < 4; ++r) {
            e[r] = __builtin_amdgcn_exp2f((scl[tid][r] - m) * 1.442695041f); s += e[r];
        }
        float inv = __builtin_amdgcn_rcpf(s);
#pragma unroll
        for (int r = 0; r < 4; ++r) al[tid][r] = e[r] * inv;
    }
    __syncthreads();

    // ---- vv -> aaux cols 64..192 (bf16) ----
    if (tid < 129) {
#pragma unroll 4
        for (int rr = 0; rr < 16; ++rr) {
            float a = 0.f;
#pragma unroll
            for (int r = 0; r < 4; ++r) {
                float val;
                if (tid < 64)       val = Mlf[rr][r][tid];
                else if (tid < 128) val = emb[rid[rr][r] * En + (tid - 64)];
                else                val = rlab[rr][r];
                a = fmaf(al[rr][r], val, a);
            }
            unsigned off = (unsigned)(rr * 512) + (((unsigned)(2 * (64 + tid))) ^ ((rr & 7) << 4));
            *(unsigned short*)(aauxB + off) = f2bf(a);
        }
    }
    __syncthreads();

    // ---- Wo GEMM (K=224 padded): ol = tanh(.) ----
    {
        f32x4 acc = {0.f, 0.f, 0.f, 0.f};
#pragma unroll
        for (int kh = 0; kh < 7; ++kh) {
            bf16x8 a = *(const bf16x8*)(aauxB + n_ * 512 + ((kh * 64 + kb * 16) ^ sw));
            bf16x8 b = *(const bf16x8*)(pWo + (w * 7 + kh) * 512 + lane * 8);
            acc = __builtin_amdgcn_mfma_f32_16x16x32_bf16(a, b, acc, 0, 0, 0);
        }
        float bov = bo[w * 16 + n_];
#pragma unroll
        for (int q = 0; q < 4; ++q) {
            int row = kb * 4 + q;
            float o = ftanh(acc[q] + bov);
            unsigned off = (unsigned)(row * 128) + (((unsigned)(2 * (w * 16 + n_))) ^ ((row & 7) << 4));
            *(unsigned short*)(olB + off) = f2bf(o);
        }
    }
    __syncthreads();

    // ---- W1 GEMM: z1 = relu(ol @ W1 + b1), N=256 (wave w -> cols w*64..) ----
    {
        bf16x8 a0 = *(const bf16x8*)(olB + n_ * 128 + ((0 * 64 + kb * 16) ^ sw));
        bf16x8 a1 = *(const bf16x8*)(olB + n_ * 128 + ((1 * 64 + kb * 16) ^ sw));
#pragma unroll
        for (int jj = 0; jj < 4; ++jj) {
            bf16x8 bb0 = *(const bf16x8*)(pW1 + ((w * 4 + jj) * 2 + 0) * 512 + lane * 8);
            bf16x8 bb1 = *(const bf16x8*)(pW1 + ((w * 4 + jj) * 2 + 1) * 512 + lane * 8);
            f32x4 z4 = {0.f, 0.f, 0.f, 0.f};
            f32x4 acc = __builtin_amdgcn_mfma_f32_16x16x32_bf16(a0, bb0, z4, 0, 0, 0);
            acc = __builtin_amdgcn_mfma_f32_16x16x32_bf16(a1, bb1, acc, 0, 0, 0);
            float b1v = b1[w * 64 + jj * 16 + n_];
#pragma unroll
            for (int q = 0; q < 4; ++q) {
                int row = kb * 4 + q;
                float z = fmaxf(acc[q] + b1v, 0.0f);
                unsigned off = (unsigned)(row * 512) +
                               (((unsigned)(2 * (w * 64 + jj * 16 + n_))) ^ ((row & 7) << 4));
                *(unsigned short*)(z1B + off) = f2bf(z);
            }
        }
    }
    __syncthreads();

    // ---- W2 GEMM: z2 = relu(z1 @ W2 + b2), K=256 ----
    {
        f32x4 acc = {0.f, 0.f, 0.f, 0.f};
#pragma unroll
        for (int kh = 0; kh < 8; ++kh) {
            bf16x8 a = *(const bf16x8*)(z1B + n_ * 512 + ((kh * 64 + kb * 16) ^ sw));
            bf16x8 b = *(const bf16x8*)(pW2 + (w * 8 + kh) * 512 + lane * 8);
            acc = __builtin_amdgcn_mfma_f32_16x16x32_bf16(a, b, acc, 0, 0, 0);
        }
        float b2v = b2[w * 16 + n_];
#pragma unroll
        for (int q = 0; q < 4; ++q)
            z2f[kb * 4 + q][w * 16 + n_] = fmaxf(acc[q] + b2v, 0.0f);
    }
    __syncthreads();

    // ---- W3 + sigmoid + y passthrough ----
    if (tid < 16) {
        float a = b3[0];
#pragma unroll 8
        for (int k = 0; k < 64; ++k) a = fmaf(z2f[tid][k], W3[k], a);
        out[r0 + tid] = fsig(a);
        out[NROW + r0 + tid] = y[r0 + tid];
    }
}

// ---------------------------------------------------------------------------
extern "C" void kernel_launch(void* const* d_in, const int* in_sizes, int n_in,
                              void* d_out, int out_size, void* d_ws, size_t ws_size,
                              hipStream_t stream) {
    const int*   intra_x   = (const int*)d_in[0];
    const int*   inter_his = (const int*)d_in[1];
    const int*   inter_r   = (const int*)d_in[2];
    const float* y         = (const float*)d_in[3];
    const int*   inter_len = (const int*)d_in[5];
    const float* emb  = (const float*)d_in[6];
    const float* Wi_h = (const float*)d_in[7];
    const float* Wh_h = (const float*)d_in[8];
    const float* bi_h = (const float*)d_in[9];
    const float* bh_h = (const float*)d_in[10];
    const float* Wi_x = (const float*)d_in[11];
    const float* Wh_x = (const float*)d_in[12];
    const float* bi_x = (const float*)d_in[13];
    const float* bh_x = (const float*)d_in[14];
    const float* Wq = (const float*)d_in[15];
    const float* Wo = (const float*)d_in[16];
    const float* bo = (const float*)d_in[17];
    const float* W1 = (const float*)d_in[18];
    const float* b1 = (const float*)d_in[19];
    const float* W2 = (const float*)d_in[20];
    const float* b2 = (const float*)d_in[21];
    const float* W3 = (const float*)d_in[22];
    const float* b3 = (const float*)d_in[23];

    float* out = (float*)d_out;
    float* ws  = (float*)d_ws;
    // workspace (floats): pre_h 192000 | xw 393216 | mrv16 262144 |
    // h_x 131072 | packs 25600  => 4.016 MB (< proven 4.157 MB)
    float*          pre_h = ws;
    float*          xw    = ws + 192000;
    unsigned short* mrv16 = (unsigned short*)(ws + 585216);
    float*          h_x   = ws + 847360;
    unsigned short* packs = (unsigned short*)(ws + 978432);

    precompute_tab<<<Vn + NROW + 100, 192, 0, stream>>>(
        emb, Wi_h, bi_h, Wi_x, bi_x, intra_x, y,
        Wq, Wo, W1, W2, pre_h, xw, packs);
    gru_fused<<<1 + NSEQ / GP, 256, 0, stream>>>(pre_h, xw, inter_his, inter_len,
                                                 Wh_h, bh_h, Wi_h,
                                                 Wh_x, bh_x,
                                                 mrv16, h_x);
    attn_mlp<<<NROW / 16, 256, 0, stream>>>(h_x, mrv16, emb, inter_r, y,
                                            packs, bo, b1, b2, W3, b3, out);
}

// Round 15
// 82.584 us; speedup vs baseline: 4.3204x; 1.0951x over previous
//
#include <hip/hip_runtime.h>
#include <hip/hip_bf16.h>
#include <math.h>

// Problem dims
#define Bn 16
#define Sn 128
#define Rn 4
#define Ln 50
#define En 64
#define Hn 64
#define Vn 1000
#define G3 192          // 3*H
#define PH1n 256
#define PH2n 64
#define NSEQ (Bn*Sn*Rn) // 8192
#define NROW (Bn*Sn)    // 2048
#define GP 16           // sequences per block (MFMA M-tile)

typedef short bf16x8 __attribute__((ext_vector_type(8)));
typedef float f32x4  __attribute__((ext_vector_type(4)));

__device__ __forceinline__ unsigned short f2bf(float x) {
    union { float f; unsigned u; } v; v.f = x;
    unsigned r = v.u + 0x7FFF + ((v.u >> 16) & 1);   // RNE
    return (unsigned short)(r >> 16);
}
__device__ __forceinline__ float bf2f(unsigned short b) {
    union { unsigned u; float f; } v; v.u = ((unsigned)b) << 16; return v.f;
}
__device__ __forceinline__ unsigned cvtpk_bf16(float lo, float hi) {
    unsigned r;
    asm volatile("v_cvt_pk_bf16_f32 %0, %1, %2" : "=v"(r) : "v"(lo), "v"(hi));
    return r;
}
// fast sigmoid/tanh: v_exp_f32 (2^x) + v_rcp_f32
__device__ __forceinline__ float fsig(float x) {
    float e = __builtin_amdgcn_exp2f(-x * 1.442695041f);
    return __builtin_amdgcn_rcpf(1.0f + e);
}
__device__ __forceinline__ float ftanh(float x) {
    float e = __builtin_amdgcn_exp2f(x * 2.885390082f);
    return 1.0f - 2.0f * __builtin_amdgcn_rcpf(e + 1.0f);
}

// Raw barrier: LDS-drain only; global loads/stores float across.
#define BAR() do { asm volatile("s_waitcnt lgkmcnt(0)" ::: "memory"); \
                   __builtin_amdgcn_s_barrier(); \
                   __builtin_amdgcn_sched_barrier(0); } while (0)

// Un-sinkable 3 gate-loads: p[0], p[64], p[128].
__device__ __forceinline__ void gload3(const float* p, float& a, float& b, float& c) {
    asm volatile("global_load_dword %0, %3, off\n\t"
                 "global_load_dword %1, %3, off offset:256\n\t"
                 "global_load_dword %2, %3, off offset:512"
                 : "=&v"(a), "=&v"(b), "=&v"(c) : "v"(p));
}

// pack table offsets (in ushorts): Wq 8 frags | Wo 28 | W1 32 | W2 32, 512 each
#define PK_WQ 0
#define PK_WO 4096
#define PK_W1 18432
#define PK_W2 34816

// ---------------------------------------------------------------------------
// Kernel A: blocks [0, Vn)            : pre_h table (f32, bh_r/bh_z folded)
//           blocks [Vn, Vn+NROW)      : xw table (f32, intra, bh folded)
//           blocks [Vn+NROW, +100)    : bf16 fragment-packed attn weights
// ---------------------------------------------------------------------------
__global__ __launch_bounds__(192) void precompute_tab(
    const float* __restrict__ emb,
    const float* __restrict__ Wi_h, const float* __restrict__ bi_h,
    const float* __restrict__ bh_h,
    const float* __restrict__ Wi_x, const float* __restrict__ bi_x,
    const float* __restrict__ bh_x,
    const int*   __restrict__ intra_x, const float* __restrict__ y,
    const float* __restrict__ Wq, const float* __restrict__ Wo,
    const float* __restrict__ W1, const float* __restrict__ W2,
    float* __restrict__ pre_h, float* __restrict__ xw,
    unsigned short* __restrict__ packs)
{
    const int bx = blockIdx.x;
    const int j = threadIdx.x;            // 0..191
    __shared__ float e_l[En];
    if (bx < Vn) {
        if (j < En) e_l[j] = emb[bx * En + j];
        __syncthreads();
        float a = bi_h[j] + (j < 128 ? bh_h[j] : 0.0f);   // fold bh_r, bh_z
#pragma unroll 8
        for (int k = 0; k < En; ++k) a = fmaf(e_l[k], Wi_h[k * G3 + j], a);
        pre_h[bx * G3 + j] = a;
    } else if (bx < Vn + NROW) {
        const int row = bx - Vn;          // row = b*Sn + t
        const int id = intra_x[row];
        const float lb = (row & (Sn - 1)) ? y[row - 1] : 0.0f;
        if (j < En) e_l[j] = emb[id * En + j];
        __syncthreads();
        float a = bi_x[j] + (j < 128 ? bh_x[j] : 0.0f);   // fold bh_r, bh_z
#pragma unroll 8
        for (int k = 0; k < En; ++k) a = fmaf(e_l[k], Wi_x[k * G3 + j], a);
        a = fmaf(lb, Wi_x[64 * G3 + j], a);
        xw[row * G3 + j] = a;
    } else if (j < 64) {
        const int p = bx - (Vn + NROW);
        const float* W; int KH, N, Kmax, q; unsigned short* dst;
        if (p < 8)       { q = p;      W = Wq; KH = 2; N = 64;  Kmax = 64;  dst = packs + PK_WQ; }
        else if (p < 36) { q = p - 8;  W = Wo; KH = 7; N = 64;  Kmax = 193; dst = packs + PK_WO; }
        else if (p < 68) { q = p - 36; W = W1; KH = 2; N = 256; Kmax = 64;  dst = packs + PK_W1; }
        else             { q = p - 68; W = W2; KH = 8; N = 64;  Kmax = 256; dst = packs + PK_W2; }
        const int nt = q / KH, kh = q - nt * KH;
        const int n  = nt * 16 + (j & 15);
        const int k0 = kh * 32 + (j >> 4) * 8;
#pragma unroll
        for (int i = 0; i < 8; ++i) {
            int k = k0 + i;
            float v = (k < Kmax) ? W[k * N + n] : 0.0f;
            dst[q * 512 + j * 8 + i] = f2bf(v);
        }
    }
}

// ---------------------------------------------------------------------------
// Kernel B: unified MFMA GRU; pre-acts enter via MFMA C-operand (bias-folded
// tables), shortening the post-MFMA gate chain to fsig/fsig/ftanh+blend.
// ---------------------------------------------------------------------------
__global__ __launch_bounds__(256, 2) void gru_fused(
    const float* __restrict__ pre_h, const float* __restrict__ xw,
    const int*   __restrict__ inter_his, const int* __restrict__ inter_len,
    const float* __restrict__ Wh_h, const float* __restrict__ bh_h,
    const float* __restrict__ Wi_h,
    const float* __restrict__ Wh_x, const float* __restrict__ bh_x,
    unsigned short* __restrict__ mrv16, float* __restrict__ h_x)
{
    __shared__ __align__(16) unsigned short h16[2][GP * 64];  // 2 x 2KB, swizzled
    __shared__ int   ids_l[GP][Ln];
    __shared__ float labs_l[GP][Ln];

    const int tid = threadIdx.x;
    const int lane = tid & 63, w = tid >> 6;
    const int n_ = lane & 15, kb = lane >> 4;
    const int jh = w * 16 + n_;
    const int rbase = kb * 4;

    const unsigned arow = (unsigned)(n_ * 128);
    const unsigned ac0  = (unsigned)((kb * 16) ^ ((n_ & 7) << 4));
    const unsigned ac1  = (unsigned)((64 + kb * 16) ^ ((n_ & 7) << 4));
    unsigned woff[4];
#pragma unroll
    for (int q = 0; q < 4; ++q) {
        int r = rbase + q;
        woff[q] = (unsigned)(r * 128 + ((jh * 2) ^ ((r & 7) << 4)));
    }
    for (int i = tid; i < GP * 64; i += 256) h16[0][i] = 0;

    if (blockIdx.x != 0) {
        // =============== PEER GRU ===============
        const int seq0 = ((int)blockIdx.x - 1) * GP;
        for (int i = tid; i < GP * Ln; i += 256) {
            int r = i / Ln, t = i % Ln;
            int base = ((seq0 + r) * Ln + t) * 2;
            ids_l[r][t]  = inter_his[base];
            labs_l[r][t] = (float)inter_his[base + 1];
        }
        bf16x8 bfr[3][2];
#pragma unroll
        for (int g = 0; g < 3; ++g)
#pragma unroll
            for (int kh = 0; kh < 2; ++kh) {
                bf16x8 v;
#pragma unroll
                for (int i = 0; i < 8; ++i)
                    v[i] = (short)f2bf(Wh_h[(kh * 32 + kb * 8 + i) * G3 + g * 64 + jh]);
                bfr[g][kh] = v;
            }
        const float bhn = bh_h[128 + jh];
        const float wlr = Wi_h[64 * G3 + jh];
        const float wlz = Wi_h[64 * G3 + 64 + jh];
        const float wln = Wi_h[64 * G3 + 128 + jh];
        int lenr[4];
#pragma unroll
        for (int q = 0; q < 4; ++q) lenr[q] = inter_len[seq0 + rbase + q];
        float hprev[4] = {0.f, 0.f, 0.f, 0.f};
        float mrvv[4] = {0.f, 0.f, 0.f, 0.f};

        float Ar[4], Az[4], An_[4], Al[4];
        float Br[4], Bz[4], Bn_[4], Bl[4];
#pragma unroll
        for (int q = 0; q < 4; ++q) {
            int id = ids_l[rbase + q][0];
            Al[q] = labs_l[rbase + q][0];
            gload3(pre_h + id * G3 + jh, Ar[q], Az[q], An_[q]);
        }
        __syncthreads();

        auto step = [&](int t, int cur,
                        float (&gr)[4], float (&gz)[4], float (&gn)[4], float (&gl)[4],
                        float (&pr)[4], float (&pz)[4], float (&pn)[4], float (&pl)[4]) {
            const char* rb = (const char*)&h16[cur][0];
            bf16x8 a0 = *(const bf16x8*)(rb + arow + ac0);
            bf16x8 a1 = *(const bf16x8*)(rb + arow + ac1);
            const int tn = (t + 1 < Ln) ? t + 1 : t;
#pragma unroll
            for (int q = 0; q < 4; ++q) {
                int id = ids_l[rbase + q][tn];
                pl[q] = labs_l[rbase + q][tn];
                gload3(pre_h + id * G3 + jh, pr[q], pz[q], pn[q]);
            }
            // previous step's gathers feed the C-operand: wait BEFORE MFMA.
            // Exactly 12 newer ops in flight (this step's loads, no stores).
            asm volatile("s_waitcnt vmcnt(12)" ::: "memory");
            __builtin_amdgcn_sched_barrier(0);
            f32x4 c0, c1, c2;
            float xn[4];
#pragma unroll
            for (int q = 0; q < 4; ++q) {
                c0[q] = fmaf(gl[q], wlr, gr[q]);
                c1[q] = fmaf(gl[q], wlz, gz[q]);
                c2[q] = bhn;
                xn[q] = fmaf(gl[q], wln, gn[q]);
            }
            f32x4 acc0 = __builtin_amdgcn_mfma_f32_16x16x32_bf16(a0, bfr[0][0], c0, 0, 0, 0);
            f32x4 acc1 = __builtin_amdgcn_mfma_f32_16x16x32_bf16(a0, bfr[1][0], c1, 0, 0, 0);
            f32x4 acc2 = __builtin_amdgcn_mfma_f32_16x16x32_bf16(a0, bfr[2][0], c2, 0, 0, 0);
            acc0 = __builtin_amdgcn_mfma_f32_16x16x32_bf16(a1, bfr[0][1], acc0, 0, 0, 0);
            acc1 = __builtin_amdgcn_mfma_f32_16x16x32_bf16(a1, bfr[1][1], acc1, 0, 0, 0);
            acc2 = __builtin_amdgcn_mfma_f32_16x16x32_bf16(a1, bfr[2][1], acc2, 0, 0, 0);

            char* wb = (char*)&h16[cur ^ 1][0];
            float hn[4];
#pragma unroll
            for (int q = 0; q < 4; ++q) {
                float rg = fsig(acc0[q]);
                float zg = fsig(acc1[q]);
                float ng = ftanh(fmaf(rg, acc2[q], xn[q]));
                float h  = ng + zg * (hprev[q] - ng);
                hprev[q] = h; hn[q] = h;
                mrvv[q] = (t == lenr[q] - 1) ? h : mrvv[q];
            }
            unsigned u01 = cvtpk_bf16(hn[0], hn[1]);
            unsigned u23 = cvtpk_bf16(hn[2], hn[3]);
            *(unsigned short*)(wb + woff[0]) = (unsigned short)u01;
            *(unsigned short*)(wb + woff[1]) = (unsigned short)(u01 >> 16);
            *(unsigned short*)(wb + woff[2]) = (unsigned short)u23;
            *(unsigned short*)(wb + woff[3]) = (unsigned short)(u23 >> 16);
            BAR();
        };

        for (int t = 0; t < Ln; t += 2) {
            step(t,     0, Ar, Az, An_, Al, Br, Bz, Bn_, Bl);
            step(t + 1, 1, Br, Bz, Bn_, Bl, Ar, Az, An_, Al);
        }
#pragma unroll
        for (int q = 0; q < 4; ++q)
            mrv16[(seq0 + rbase + q) * Hn + jh] = f2bf(mrvv[q]);
    } else {
        // =============== INTRA GRU (linear xw reads, C-init) ===============
        bf16x8 bfr[3][2];
#pragma unroll
        for (int g = 0; g < 3; ++g)
#pragma unroll
            for (int kh = 0; kh < 2; ++kh) {
                bf16x8 v;
#pragma unroll
                for (int i = 0; i < 8; ++i)
                    v[i] = (short)f2bf(Wh_x[(kh * 32 + kb * 8 + i) * G3 + g * 64 + jh]);
                bfr[g][kh] = v;
            }
        const float bhn = bh_x[128 + jh];
        float hprev[4] = {0.f, 0.f, 0.f, 0.f};

        const float* q0 = xw + (rbase + 0) * Sn * G3 + jh;
        const float* q1 = xw + (rbase + 1) * Sn * G3 + jh;
        const float* q2 = xw + (rbase + 2) * Sn * G3 + jh;
        const float* q3 = xw + (rbase + 3) * Sn * G3 + jh;
        float* p0 = h_x + (rbase + 0) * Sn * Hn + jh;
        float* p1 = h_x + (rbase + 1) * Sn * Hn + jh;
        float* p2 = h_x + (rbase + 2) * Sn * Hn + jh;
        float* p3 = h_x + (rbase + 3) * Sn * Hn + jh;

        float Ar[4], Az[4], An_[4];
        float Br[4], Bz[4], Bn_[4];
        gload3(q0, Ar[0], Az[0], An_[0]);
        gload3(q1, Ar[1], Az[1], An_[1]);
        gload3(q2, Ar[2], Az[2], An_[2]);
        gload3(q3, Ar[3], Az[3], An_[3]);
        __syncthreads();

        auto istep = [&](int t, int cur,
                         float (&gr)[4], float (&gz)[4], float (&gn)[4],
                         float (&pr)[4], float (&pz)[4], float (&pn)[4]) {
            const char* rb = (const char*)&h16[cur][0];
            bf16x8 a0 = *(const bf16x8*)(rb + arow + ac0);
            bf16x8 a1 = *(const bf16x8*)(rb + arow + ac1);
            if (t + 1 < Sn) { q0 += G3; q1 += G3; q2 += G3; q3 += G3; }
            gload3(q0, pr[0], pz[0], pn[0]);
            gload3(q1, pr[1], pz[1], pn[1]);
            gload3(q2, pr[2], pz[2], pn[2]);
            gload3(q3, pr[3], pz[3], pn[3]);
            // S_{t-1}(4 stores) + L_{t+1}(12) = 16 newer ops; retires L_t.
            asm volatile("s_waitcnt vmcnt(16)" ::: "memory");
            __builtin_amdgcn_sched_barrier(0);
            f32x4 c0 = {gr[0], gr[1], gr[2], gr[3]};
            f32x4 c1 = {gz[0], gz[1], gz[2], gz[3]};
            f32x4 c2 = {bhn, bhn, bhn, bhn};
            f32x4 acc0 = __builtin_amdgcn_mfma_f32_16x16x32_bf16(a0, bfr[0][0], c0, 0, 0, 0);
            f32x4 acc1 = __builtin_amdgcn_mfma_f32_16x16x32_bf16(a0, bfr[1][0], c1, 0, 0, 0);
            f32x4 acc2 = __builtin_amdgcn_mfma_f32_16x16x32_bf16(a0, bfr[2][0], c2, 0, 0, 0);
            acc0 = __builtin_amdgcn_mfma_f32_16x16x32_bf16(a1, bfr[0][1], acc0, 0, 0, 0);
            acc1 = __builtin_amdgcn_mfma_f32_16x16x32_bf16(a1, bfr[1][1], acc1, 0, 0, 0);
            acc2 = __builtin_amdgcn_mfma_f32_16x16x32_bf16(a1, bfr[2][1], acc2, 0, 0, 0);

            char* wb = (char*)&h16[cur ^ 1][0];
            float hn[4];
#pragma unroll
            for (int q = 0; q < 4; ++q) {
                float rg = fsig(acc0[q]);
                float zg = fsig(acc1[q]);
                float ng = ftanh(fmaf(rg, acc2[q], gn[q]));
                float h  = ng + zg * (hprev[q] - ng);
                hprev[q] = h; hn[q] = h;
            }
            unsigned u01 = cvtpk_bf16(hn[0], hn[1]);
            unsigned u23 = cvtpk_bf16(hn[2], hn[3]);
            *(unsigned short*)(wb + woff[0]) = (unsigned short)u01;
            *(unsigned short*)(wb + woff[1]) = (unsigned short)(u01 >> 16);
            *(unsigned short*)(wb + woff[2]) = (unsigned short)u23;
            *(unsigned short*)(wb + woff[3]) = (unsigned short)(u23 >> 16);
            *p0 = hn[0]; p0 += Hn;
            *p1 = hn[1]; p1 += Hn;
            *p2 = hn[2]; p2 += Hn;
            *p3 = hn[3]; p3 += Hn;
            BAR();
        };

        for (int t = 0; t < Sn; t += 2) {
            istep(t,     0, Ar, Az, An_, Br, Bz, Bn_);
            istep(t + 1, 1, Br, Bz, Bn_, Ar, Az, An_);
        }
    }
}

// ---------------------------------------------------------------------------
// Kernel C: MFMA attention + MLP; 16 rows per block, 128 blocks. (round 14)
// ---------------------------------------------------------------------------
__global__ __launch_bounds__(256) void attn_mlp(
    const float* __restrict__ h_x, const unsigned short* __restrict__ mrv16,
    const float* __restrict__ emb, const int* __restrict__ inter_r,
    const float* __restrict__ y,
    const unsigned short* __restrict__ packs,
    const float* __restrict__ bo, const float* __restrict__ b1,
    const float* __restrict__ b2,
    const float* __restrict__ W3, const float* __restrict__ b3,
    float* __restrict__ out)
{
    const int r0 = blockIdx.x * 16;
    const int tid = threadIdx.x;
    const int lane = tid & 63, w = tid >> 6;
    const int n_ = lane & 15, kb = lane >> 4;
    const unsigned sw = (unsigned)((n_ & 7) << 4);

    __shared__ __align__(16) char aauxB[16 * 512];   // [16][256] bf16: h|vv|0
    __shared__ __align__(16) char olB[16 * 128];     // [16][64]  bf16
    __shared__ __align__(16) char z1B[16 * 512];     // [16][256] bf16
    __shared__ float Mlf[16][4][65];
    __shared__ float qs[16][68];
    __shared__ float z2f[16][68];
    __shared__ float scl[16][4], al[16][4], rlab[16][4];
    __shared__ int   rid[16][4];

    const unsigned short* pWq = packs + PK_WQ;
    const unsigned short* pWo = packs + PK_WO;
    const unsigned short* pW1 = packs + PK_W1;
    const unsigned short* pW2 = packs + PK_W2;

    for (int i = tid; i < 16 * 96; i += 256) {
        int rr = i / 96, d = 32 + (i % 96);
        ((unsigned*)aauxB)[rr * 128 + d] = 0;
    }
    {
        int rr = tid >> 4, c4 = (tid & 15) * 4;
        float4 hv = *(const float4*)(h_x + (r0 + rr) * Hn + c4);
        unsigned lo = cvtpk_bf16(hv.x, hv.y), hi = cvtpk_bf16(hv.z, hv.w);
        unsigned off = (unsigned)(rr * 512) + (((unsigned)(2 * c4)) ^ ((rr & 7) << 4));
        *(unsigned*)(aauxB + off) = lo;
        *(unsigned*)(aauxB + off + 4) = hi;
    }
    for (int i = tid; i < 4096; i += 256) {
        int rr = i >> 8, rem = i & 255, r = rem >> 6, k = rem & 63;
        Mlf[rr][r][k] = bf2f(mrv16[((r0 + rr) * Rn + r) * Hn + k]);
    }
    if (tid < 64) {
        int rr = tid >> 2, r = tid & 3;
        rid[rr][r]  = inter_r[((r0 + rr) * Rn + r) * 2];
        rlab[rr][r] = (float)inter_r[((r0 + rr) * Rn + r) * 2 + 1];
    }
    __syncthreads();

    {
        bf16x8 a0 = *(const bf16x8*)(aauxB + n_ * 512 + ((0 * 64 + kb * 16) ^ sw));
        bf16x8 a1 = *(const bf16x8*)(aauxB + n_ * 512 + ((1 * 64 + kb * 16) ^ sw));
        bf16x8 b0 = *(const bf16x8*)(pWq + (w * 2 + 0) * 512 + lane * 8);
        bf16x8 b1v = *(const bf16x8*)(pWq + (w * 2 + 1) * 512 + lane * 8);
        f32x4 z4 = {0.f, 0.f, 0.f, 0.f};
        f32x4 qa = __builtin_amdgcn_mfma_f32_16x16x32_bf16(a0, b0, z4, 0, 0, 0);
        qa = __builtin_amdgcn_mfma_f32_16x16x32_bf16(a1, b1v, qa, 0, 0, 0);
#pragma unroll
        for (int q = 0; q < 4; ++q) qs[kb * 4 + q][w * 16 + n_] = qa[q];
    }
    __syncthreads();

    if (tid < 64) {
        int rr = tid >> 2, r = tid & 3;
        float a = 0.f;
#pragma unroll 8
        for (int k = 0; k < 64; ++k) a = fmaf(qs[rr][k], Mlf[rr][r][k], a);
        scl[rr][r] = a * 0.125f;
    }
    __syncthreads();
    if (tid < 16) {
        float m = fmaxf(fmaxf(scl[tid][0], scl[tid][1]), fmaxf(scl[tid][2], scl[tid][3]));
        float s = 0.f, e[4];
#pragma unroll
        for (int r = 0; r < 4; ++r) {
            e[r] = __builtin_amdgcn_exp2f((scl[tid][r] - m) * 1.442695041f); s += e[r];
        }
        float inv = __builtin_amdgcn_rcpf(s);
#pragma unroll
        for (int r = 0; r < 4; ++r) al[tid][r] = e[r] * inv;
    }
    __syncthreads();

    if (tid < 129) {
#pragma unroll 4
        for (int rr = 0; rr < 16; ++rr) {
            float a = 0.f;
#pragma unroll
            for (int r = 0; r < 4; ++r) {
                float val;
                if (tid < 64)       val = Mlf[rr][r][tid];
                else if (tid < 128) val = emb[rid[rr][r] * En + (tid - 64)];
                else                val = rlab[rr][r];
                a = fmaf(al[rr][r], val, a);
            }
            unsigned off = (unsigned)(rr * 512) + (((unsigned)(2 * (64 + tid))) ^ ((rr & 7) << 4));
            *(unsigned short*)(aauxB + off) = f2bf(a);
        }
    }
    __syncthreads();

    {
        f32x4 acc = {0.f, 0.f, 0.f, 0.f};
#pragma unroll
        for (int kh = 0; kh < 7; ++kh) {
            bf16x8 a = *(const bf16x8*)(aauxB + n_ * 512 + ((kh * 64 + kb * 16) ^ sw));
            bf16x8 b = *(const bf16x8*)(pWo + (w * 7 + kh) * 512 + lane * 8);
            acc = __builtin_amdgcn_mfma_f32_16x16x32_bf16(a, b, acc, 0, 0, 0);
        }
        float bov = bo[w * 16 + n_];
#pragma unroll
        for (int q = 0; q < 4; ++q) {
            int row = kb * 4 + q;
            float o = ftanh(acc[q] + bov);
            unsigned off = (unsigned)(row * 128) + (((unsigned)(2 * (w * 16 + n_))) ^ ((row & 7) << 4));
            *(unsigned short*)(olB + off) = f2bf(o);
        }
    }
    __syncthreads();

    {
        bf16x8 a0 = *(const bf16x8*)(olB + n_ * 128 + ((0 * 64 + kb * 16) ^ sw));
        bf16x8 a1 = *(const bf16x8*)(olB + n_ * 128 + ((1 * 64 + kb * 16) ^ sw));
#pragma unroll
        for (int jj = 0; jj < 4; ++jj) {
            bf16x8 bb0 = *(const bf16x8*)(pW1 + ((w * 4 + jj) * 2 + 0) * 512 + lane * 8);
            bf16x8 bb1 = *(const bf16x8*)(pW1 + ((w * 4 + jj) * 2 + 1) * 512 + lane * 8);
            f32x4 z4 = {0.f, 0.f, 0.f, 0.f};
            f32x4 acc = __builtin_amdgcn_mfma_f32_16x16x32_bf16(a0, bb0, z4, 0, 0, 0);
            acc = __builtin_amdgcn_mfma_f32_16x16x32_bf16(a1, bb1, acc, 0, 0, 0);
            float b1v = b1[w * 64 + jj * 16 + n_];
#pragma unroll
            for (int q = 0; q < 4; ++q) {
                int row = kb * 4 + q;
                float z = fmaxf(acc[q] + b1v, 0.0f);
                unsigned off = (unsigned)(row * 512) +
                               (((unsigned)(2 * (w * 64 + jj * 16 + n_))) ^ ((row & 7) << 4));
                *(unsigned short*)(z1B + off) = f2bf(z);
            }
        }
    }
    __syncthreads();

    {
        f32x4 acc = {0.f, 0.f, 0.f, 0.f};
#pragma unroll
        for (int kh = 0; kh < 8; ++kh) {
            bf16x8 a = *(const bf16x8*)(z1B + n_ * 512 + ((kh * 64 + kb * 16) ^ sw));
            bf16x8 b = *(const bf16x8*)(pW2 + (w * 8 + kh) * 512 + lane * 8);
            acc = __builtin_amdgcn_mfma_f32_16x16x32_bf16(a, b, acc, 0, 0, 0);
        }
        float b2v = b2[w * 16 + n_];
#pragma unroll
        for (int q = 0; q < 4; ++q)
            z2f[kb * 4 + q][w * 16 + n_] = fmaxf(acc[q] + b2v, 0.0f);
    }
    __syncthreads();

    if (tid < 16) {
        float a = b3[0];
#pragma unroll 8
        for (int k = 0; k < 64; ++k) a = fmaf(z2f[tid][k], W3[k], a);
        out[r0 + tid] = fsig(a);
        out[NROW + r0 + tid] = y[r0 + tid];
    }
}

// ---------------------------------------------------------------------------
extern "C" void kernel_launch(void* const* d_in, const int* in_sizes, int n_in,
                              void* d_out, int out_size, void* d_ws, size_t ws_size,
                              hipStream_t stream) {
    const int*   intra_x   = (const int*)d_in[0];
    const int*   inter_his = (const int*)d_in[1];
    const int*   inter_r   = (const int*)d_in[2];
    const float* y         = (const float*)d_in[3];
    const int*   inter_len = (const int*)d_in[5];
    const float* emb  = (const float*)d_in[6];
    const float* Wi_h = (const float*)d_in[7];
    const float* Wh_h = (const float*)d_in[8];
    const float* bi_h = (const float*)d_in[9];
    const float* bh_h = (const float*)d_in[10];
    const float* Wi_x = (const float*)d_in[11];
    const float* Wh_x = (const float*)d_in[12];
    const float* bi_x = (const float*)d_in[13];
    const float* bh_x = (const float*)d_in[14];
    const float* Wq = (const float*)d_in[15];
    const float* Wo = (const float*)d_in[16];
    const float* bo = (const float*)d_in[17];
    const float* W1 = (const float*)d_in[18];
    const float* b1 = (const float*)d_in[19];
    const float* W2 = (const float*)d_in[20];
    const float* b2 = (const float*)d_in[21];
    const float* W3 = (const float*)d_in[22];
    const float* b3 = (const float*)d_in[23];

    float* out = (float*)d_out;
    float* ws  = (float*)d_ws;
    // workspace (floats): pre_h 192000 | xw 393216 | mrv16 262144 |
    // h_x 131072 | packs 25600  => 4.016 MB (proven size)
    float*          pre_h = ws;
    float*          xw    = ws + 192000;
    unsigned short* mrv16 = (unsigned short*)(ws + 585216);
    float*          h_x   = ws + 847360;
    unsigned short* packs = (unsigned short*)(ws + 978432);

    precompute_tab<<<Vn + NROW + 100, 192, 0, stream>>>(
        emb, Wi_h, bi_h, bh_h, Wi_x, bi_x, bh_x, intra_x, y,
        Wq, Wo, W1, W2, pre_h, xw, packs);
    gru_fused<<<1 + NSEQ / GP, 256, 0, stream>>>(pre_h, xw, inter_his, inter_len,
                                                 Wh_h, bh_h, Wi_h,
                                                 Wh_x, bh_x,
                                                 mrv16, h_x);
    attn_mlp<<<NROW / 16, 256, 0, stream>>>(h_x, mrv16, emb, inter_r, y,
                                            packs, bo, b1, b2, W3, b3, out);
}